// Round 7
// baseline (367.767 us; speedup 1.0000x reference)
//
#include <hip/hip_runtime.h>

#define DIMC 1024
#define NSEQ 8192
#define DH 64

typedef __attribute__((ext_vector_type(8))) short short8;
typedef __attribute__((ext_vector_type(4))) float f32x4;

__device__ __forceinline__ short f2bf(float f) {
  union { float f; unsigned u; } v; v.f = f;
  unsigned r = v.u + 0x7FFFu + ((v.u >> 16) & 1u);
  return (short)(r >> 16);
}

// pack two fp32 -> two bf16 (lo = a, hi = b); round-half-up, matches bfbits()
__device__ __forceinline__ unsigned pack_bf2(float a, float b) {
  union { float f; unsigned u; } va, vb;
  va.f = a; vb.f = b;
  unsigned ua = va.u + 0x8000u;
  unsigned ub = vb.u + 0x8000u;
  return (ua >> 16) | (ub & 0xFFFF0000u);
}

__device__ __forceinline__ unsigned bfbits(float f) {
  union { float f; unsigned u; } v; v.f = f;
  return (v.u + 0x8000u) >> 16;  // same rounding as pack_bf2
}
__device__ __forceinline__ float bf2f(unsigned hb) {
  union { unsigned u; float f; } v; v.u = hb << 16;
  return v.f;
}

__device__ __forceinline__ void gload_lds16(const void* g, void* l) {
  __builtin_amdgcn_global_load_lds(
      (const __attribute__((address_space(1))) void*)g,
      (__attribute__((address_space(3))) void*)l, 16, 0, 0);
}

// ---------------- Stage 1 (big path): MFMA Gram via hi/lo bf16 split -------
// G = X^T X per (b,h). x = x_hi + x_lo (bf16 each); G ~= H^T H + H^T L + L^T H
// (dropped L^T L ~ 2^-18 relative). Grid (8 chunks, 64 bh), 4 waves.
// In-block LDS reduction of the 4 wave-partials -> 8 global partials.
__global__ __launch_bounds__(256) void gram2_kernel(const float* __restrict__ x,
                                                    float* __restrict__ Gpart,
                                                    short* __restrict__ xbf) {
  int chunk = blockIdx.x, bh = blockIdx.y;
  int b = bh >> 4, h = bh & 15;
  int t = threadIdx.x;
  int w = t >> 6, l = t & 63;
  int quad = l >> 4, ln = l & 15;

  __shared__ __align__(16) short XT[4][2][64 * 32];  // [wave][hi/lo][d][k] 32 KiB
  __shared__ __align__(16) float Pred[3][4096];      // wave 1..3 partials, 48 KiB
  short* XH = &XT[w][0][0];
  short* XL = &XT[w][1][0];

  size_t rowbase = (size_t)b * NSEQ + (size_t)chunk * 1024 + w * 256;
  const float* xb = x + rowbase * DIMC + h * DH;
  short* xo = xbf + rowbase * DIMC + h * DH;

  f32x4 acc[4][4];
#pragma unroll
  for (int i = 0; i < 4; i++)
#pragma unroll
    for (int j = 0; j < 4; j++) acc[i][j] = (f32x4){0.f, 0.f, 0.f, 0.f};

  int woff[4][4];
#pragma unroll
  for (int q = 0; q < 4; q++) {
    int kk = 8 * q + 2 * quad;
    int kp = kk ^ ((ln & 3) << 3);
#pragma unroll
    for (int i = 0; i < 4; i++) {
      int d = ln * 4 + i;
      woff[q][i] = d * 32 + kp;
    }
  }
  int roff[4];
  {
    int k0 = (quad * 8) ^ ((ln >> 2) << 3);
#pragma unroll
    for (int i = 0; i < 4; i++) roff[i] = (i * 16 + ln) * 32 + k0;
  }

  float4 cur[4][2];
#pragma unroll
  for (int q = 0; q < 4; q++)
#pragma unroll
    for (int r = 0; r < 2; r++)
      cur[q][r] = *(const float4*)(xb + (size_t)(8 * q + 2 * quad + r) * DIMC + ln * 4);

  for (int ks = 0; ks < 8; ks++) {
    float4 nxt[4][2];
    if (ks < 7) {
      int nb = (ks + 1) * 32;
#pragma unroll
      for (int q = 0; q < 4; q++)
#pragma unroll
        for (int r = 0; r < 2; r++)
          nxt[q][r] = *(const float4*)(xb + (size_t)(nb + 8 * q + 2 * quad + r) * DIMC + ln * 4);
    }
#pragma unroll
    for (int q = 0; q < 4; q++) {
      unsigned h0[4], h1[4], l0[4], l1[4];
#pragma unroll
      for (int i = 0; i < 4; i++) {
        float a = cur[q][0][i], bb = cur[q][1][i];
        h0[i] = bfbits(a); l0[i] = bfbits(a - bf2f(h0[i]));
        h1[i] = bfbits(bb); l1[i] = bfbits(bb - bf2f(h1[i]));
      }
      int grow = ks * 32 + 8 * q + 2 * quad;
      uint2 p0 = {h0[0] | (h0[1] << 16), h0[2] | (h0[3] << 16)};
      uint2 p1 = {h1[0] | (h1[1] << 16), h1[2] | (h1[3] << 16)};
      *(uint2*)(xo + (size_t)grow * DIMC + ln * 4) = p0;
      *(uint2*)(xo + (size_t)(grow + 1) * DIMC + ln * 4) = p1;
#pragma unroll
      for (int i = 0; i < 4; i++) {
        *(unsigned*)&XH[woff[q][i]] = h0[i] | (h1[i] << 16);
        *(unsigned*)&XL[woff[q][i]] = l0[i] | (l1[i] << 16);
      }
    }
    short8 hf[4], lf[4];
#pragma unroll
    for (int i = 0; i < 4; i++) {
      hf[i] = *(const short8*)&XH[roff[i]];
      lf[i] = *(const short8*)&XL[roff[i]];
    }
#pragma unroll
    for (int i = 0; i < 4; i++)
#pragma unroll
      for (int j = 0; j < 4; j++) {
        acc[i][j] = __builtin_amdgcn_mfma_f32_16x16x32_bf16(hf[i], hf[j], acc[i][j], 0, 0, 0);
        acc[i][j] = __builtin_amdgcn_mfma_f32_16x16x32_bf16(hf[i], lf[j], acc[i][j], 0, 0, 0);
        acc[i][j] = __builtin_amdgcn_mfma_f32_16x16x32_bf16(lf[i], hf[j], acc[i][j], 0, 0, 0);
      }
#pragma unroll
    for (int q = 0; q < 4; q++)
#pragma unroll
      for (int r = 0; r < 2; r++) cur[q][r] = nxt[q][r];
  }

  // in-block reduction: waves 1-3 park partials in LDS, wave 0 merges + stores
  if (w > 0) {
    float* pd = &Pred[w - 1][0];
#pragma unroll
    for (int i = 0; i < 4; i++)
#pragma unroll
      for (int j = 0; j < 4; j++)
#pragma unroll
        for (int r = 0; r < 4; r++) {
          int d = i * 16 + quad * 4 + r, e = j * 16 + ln;
          pd[d * 64 + e] = acc[i][j][r];
        }
  }
  __syncthreads();
  if (w == 0) {
    float* gp = Gpart + (size_t)chunk * (64 * 4096) + (size_t)bh * 4096;
#pragma unroll
    for (int i = 0; i < 4; i++)
#pragma unroll
      for (int j = 0; j < 4; j++)
#pragma unroll
        for (int r = 0; r < 4; r++) {
          int d = i * 16 + quad * 4 + r, e = j * 16 + ln;
          int idx = d * 64 + e;
          gp[idx] = acc[i][j][r] + Pred[0][idx] + Pred[1][idx] + Pred[2][idx];
        }
  }
}

// ---------------- Stage 1 (fallback): fp32 Gram, no xbf ---------------------
__global__ __launch_bounds__(64) void gram_kernel(const float* __restrict__ x,
                                                  float* __restrict__ Gpart,
                                                  short* __restrict__ xbf) {
  int chunk = blockIdx.x, bh = blockIdx.y;
  int b = bh >> 4, h = bh & 15;
  int t = threadIdx.x;
  __shared__ __align__(16) float rows[16 * 64];
  const float* xb = x + ((size_t)b * NSEQ) * DIMC + h * DH;
  short* xo = xbf ? xbf + ((size_t)b * NSEQ) * DIMC + h * DH : (short*)0;
  int d0 = (t >> 3) * 8, e0 = (t & 7) * 8;
  float acc[8][8] = {};
  float4 v[4];
#pragma unroll
  for (int i = 0; i < 4; i++) {
    int f4 = i * 64 + t;
    v[i] = *(const float4*)(xb + (size_t)(chunk * 256 + (f4 >> 4)) * DIMC + (f4 & 15) * 4);
  }
  for (int it = 0; it < 16; it++) {
    __syncthreads();
#pragma unroll
    for (int i = 0; i < 4; i++) ((float4*)rows)[i * 64 + t] = v[i];
    __syncthreads();
    if (xo) {
#pragma unroll
      for (int i = 0; i < 4; i++) {
        int f4 = i * 64 + t;
        int row = chunk * 256 + it * 16 + (f4 >> 4), col = (f4 & 15) * 4;
        uint2 pw = {pack_bf2(v[i].x, v[i].y), pack_bf2(v[i].z, v[i].w)};
        *(uint2*)(xo + (size_t)row * DIMC + col) = pw;
      }
    }
    if (it < 15) {
      int nbase = chunk * 256 + (it + 1) * 16;
#pragma unroll
      for (int i = 0; i < 4; i++) {
        int f4 = i * 64 + t;
        v[i] = *(const float4*)(xb + (size_t)(nbase + (f4 >> 4)) * DIMC + (f4 & 15) * 4);
      }
    }
#pragma unroll
    for (int r = 0; r < 16; r++) {
      float xd[8], xe[8];
      *(float4*)&xd[0] = *(const float4*)&rows[r * 64 + d0];
      *(float4*)&xd[4] = *(const float4*)&rows[r * 64 + d0 + 4];
      *(float4*)&xe[0] = *(const float4*)&rows[r * 64 + e0];
      *(float4*)&xe[4] = *(const float4*)&rows[r * 64 + e0 + 4];
#pragma unroll
      for (int i = 0; i < 8; i++)
#pragma unroll
        for (int j = 0; j < 8; j++) acc[i][j] = fmaf(xd[i], xe[j], acc[i][j]);
    }
  }
  float* gp = Gpart + (size_t)chunk * (64 * 4096) + (size_t)bh * 4096;
#pragma unroll
  for (int i = 0; i < 8; i++)
#pragma unroll
    for (int j = 0; j < 8; j++) gp[(d0 + i) * 64 + e0 + j] = acc[i][j];
}

// ---------------- Stage 1b (fallback only): reduce np partials -> G ---------
__global__ void reduce_g(const float* __restrict__ Gpart, float* __restrict__ G,
                         int np) {
  int i = blockIdx.x * 256 + threadIdx.x;
  float s = 0.f;
  for (int p = 0; p < np; p++) s += Gpart[(size_t)p * (64 * 4096) + i];
  G[i] = s;
}

// ---------------- Stage 2a (big path): M per bh, computed ONCE --------------
// Fuses the 8-partial reduction (same sum order as reduce_g -> bit-identical)
// and the T1/T2/M chain that combine_kernel previously recomputed 8x per bh.
__global__ __launch_bounds__(256) void compute_m_kernel(
    const float* __restrict__ Gpart, const float* __restrict__ Wq,
    const float* __restrict__ Wk, const float* __restrict__ Wv,
    float* __restrict__ M) {
  int bh = blockIdx.x;
  int t = threadIdx.x;
  __shared__ __align__(16) float sG[4096];
  __shared__ __align__(16) float sW[4096];
  __shared__ __align__(16) float sA[4096];

  for (int i = t; i < 4096; i += 256) {
    float s = 0.f;
#pragma unroll
    for (int p = 0; p < 8; p++)
      s += Gpart[(size_t)p * (64 * 4096) + (size_t)bh * 4096 + i];
    sG[i] = s;
  }
  for (int i = t; i < 4096; i += 256) sW[i] = Wk[i];
  __syncthreads();

  int d0 = (t >> 4) * 4, e0 = (t & 15) * 4;
  // T1 = Wk * G -> sA
  {
    float a[4][4] = {};
    for (int fg = 0; fg < 16; fg++) {
      float wk[4][4], g4[4][4];
#pragma unroll
      for (int i = 0; i < 4; i++) *(float4*)wk[i] = *(const float4*)&sW[(d0 + i) * 64 + fg * 4];
#pragma unroll
      for (int ff = 0; ff < 4; ff++) *(float4*)g4[ff] = *(const float4*)&sG[(fg * 4 + ff) * 64 + e0];
#pragma unroll
      for (int i = 0; i < 4; i++)
#pragma unroll
        for (int ff = 0; ff < 4; ff++)
#pragma unroll
          for (int j = 0; j < 4; j++) a[i][j] = fmaf(wk[i][ff], g4[ff][j], a[i][j]);
    }
#pragma unroll
    for (int i = 0; i < 4; i++)
#pragma unroll
      for (int j = 0; j < 4; j++) sA[(d0 + i) * 64 + e0 + j] = a[i][j];
  }
  __syncthreads();
  for (int i = t; i < 4096; i += 256) sW[i] = Wv[i];
  __syncthreads();
  // T2 = T1 * Wv^T -> sG
  {
    float a[4][4] = {};
    for (int fgi = 0; fgi < 16; fgi++) {
      int fg = (fgi + (t & 15)) & 15;
      float t1[4][4], wv[4][4];
#pragma unroll
      for (int i = 0; i < 4; i++) *(float4*)t1[i] = *(const float4*)&sA[(d0 + i) * 64 + fg * 4];
#pragma unroll
      for (int j = 0; j < 4; j++) *(float4*)wv[j] = *(const float4*)&sW[(e0 + j) * 64 + fg * 4];
#pragma unroll
      for (int i = 0; i < 4; i++)
#pragma unroll
        for (int j = 0; j < 4; j++)
#pragma unroll
          for (int ff = 0; ff < 4; ff++) a[i][j] = fmaf(t1[i][ff], wv[j][ff], a[i][j]);
    }
    __syncthreads();
#pragma unroll
    for (int i = 0; i < 4; i++)
#pragma unroll
      for (int j = 0; j < 4; j++) sG[(d0 + i) * 64 + e0 + j] = a[i][j];
  }
  __syncthreads();
  for (int i = t; i < 4096; i += 256) sW[i] = Wq[i];
  __syncthreads();
  // M = Wq^T * T2 / N -> global
  {
    float a[4][4] = {};
    for (int f = 0; f < 64; f++) {
      float wq[4], t2[4];
      *(float4*)wq = *(const float4*)&sW[f * 64 + d0];
      *(float4*)t2 = *(const float4*)&sG[f * 64 + e0];
#pragma unroll
      for (int i = 0; i < 4; i++)
#pragma unroll
        for (int j = 0; j < 4; j++) a[i][j] = fmaf(wq[i], t2[j], a[i][j]);
    }
    float* mo = M + (size_t)bh * 4096;
#pragma unroll
    for (int i = 0; i < 4; i++)
#pragma unroll
      for (int j = 0; j < 4; j++)
        mo[(d0 + i) * 64 + e0 + j] = a[i][j] * (1.0f / 8192.0f);
  }
}

// ---------------- Stage 2b (big path): WbigT from M + Wo --------------------
// Identical Wo-projection loop as old combine_kernel; M loaded from global.
__global__ __launch_bounds__(256) void wbig_kernel(
    const float* __restrict__ M, const float* __restrict__ Wo,
    short* __restrict__ WbigT) {
  int bh = blockIdx.x, qt = blockIdx.y;
  int b = bh >> 4, h = bh & 15;
  int t = threadIdx.x;
  __shared__ __align__(16) float sM[4096];
  __shared__ __align__(16) float sW[4096];

  for (int i = t; i < 4096; i += 256) sM[i] = M[(size_t)bh * 4096 + i];

  int dd0 = (t & 15) * 4, cl0 = (t >> 4) * 4;
  for (int cc = qt * 2; cc < qt * 2 + 2; cc++) {
    int c0 = cc * 64;
    for (int i = t; i < 4096; i += 256)
      sW[i] = Wo[(size_t)(c0 + (i >> 6)) * DIMC + h * DH + (i & 63)];
    __syncthreads();
    float a[4][4] = {};
    for (int egi = 0; egi < 16; egi++) {
      int eg = (egi + (t & 15)) & 15;
      float m4[4][4], wo4[4][4];
#pragma unroll
      for (int i = 0; i < 4; i++) *(float4*)m4[i] = *(const float4*)&sM[(dd0 + i) * 64 + eg * 4];
#pragma unroll
      for (int j = 0; j < 4; j++) *(float4*)wo4[j] = *(const float4*)&sW[(cl0 + j) * 64 + eg * 4];
#pragma unroll
      for (int i = 0; i < 4; i++)
#pragma unroll
        for (int j = 0; j < 4; j++)
#pragma unroll
          for (int ff = 0; ff < 4; ff++) a[i][j] = fmaf(m4[i][ff], wo4[j][ff], a[i][j]);
    }
#pragma unroll
    for (int j = 0; j < 4; j++) {
      uint2 pw = {pack_bf2(a[0][j], a[1][j]), pack_bf2(a[2][j], a[3][j])};
      *(uint2*)&WbigT[((size_t)b << 20) + (size_t)(c0 + cl0 + j) * DIMC + h * DH + dd0] = pw;
    }
    __syncthreads();
  }
}

// ---------------- Stage 2 (fallback): original fused combine ----------------
__global__ __launch_bounds__(256) void combine_kernel(
    const float* __restrict__ G, const float* __restrict__ Wq,
    const float* __restrict__ Wk, const float* __restrict__ Wv,
    const float* __restrict__ Wo, short* __restrict__ WbigT) {
  int bh = blockIdx.x, qt = blockIdx.y;
  int b = bh >> 4, h = bh & 15;
  int t = threadIdx.x;
  __shared__ __align__(16) float sG[4096];
  __shared__ __align__(16) float sW[4096];
  __shared__ __align__(16) float sA[4096];
  __shared__ __align__(16) float sM[4096];

  for (int i = t; i < 4096; i += 256) sG[i] = G[(size_t)bh * 4096 + i];
  for (int i = t; i < 4096; i += 256) sW[i] = Wk[i];
  __syncthreads();

  int d0 = (t >> 4) * 4, e0 = (t & 15) * 4;
  {
    float a[4][4] = {};
    for (int fg = 0; fg < 16; fg++) {
      float wk[4][4], g4[4][4];
#pragma unroll
      for (int i = 0; i < 4; i++) *(float4*)wk[i] = *(const float4*)&sW[(d0 + i) * 64 + fg * 4];
#pragma unroll
      for (int ff = 0; ff < 4; ff++) *(float4*)g4[ff] = *(const float4*)&sG[(fg * 4 + ff) * 64 + e0];
#pragma unroll
      for (int i = 0; i < 4; i++)
#pragma unroll
        for (int ff = 0; ff < 4; ff++)
#pragma unroll
          for (int j = 0; j < 4; j++) a[i][j] = fmaf(wk[i][ff], g4[ff][j], a[i][j]);
    }
#pragma unroll
    for (int i = 0; i < 4; i++)
#pragma unroll
      for (int j = 0; j < 4; j++) sA[(d0 + i) * 64 + e0 + j] = a[i][j];
  }
  __syncthreads();
  for (int i = t; i < 4096; i += 256) sW[i] = Wv[i];
  __syncthreads();
  {
    float a[4][4] = {};
    for (int fgi = 0; fgi < 16; fgi++) {
      int fg = (fgi + (t & 15)) & 15;
      float t1[4][4], wv[4][4];
#pragma unroll
      for (int i = 0; i < 4; i++) *(float4*)t1[i] = *(const float4*)&sA[(d0 + i) * 64 + fg * 4];
#pragma unroll
      for (int j = 0; j < 4; j++) *(float4*)wv[j] = *(const float4*)&sW[(e0 + j) * 64 + fg * 4];
#pragma unroll
      for (int i = 0; i < 4; i++)
#pragma unroll
        for (int j = 0; j < 4; j++)
#pragma unroll
          for (int ff = 0; ff < 4; ff++) a[i][j] = fmaf(t1[i][ff], wv[j][ff], a[i][j]);
    }
    __syncthreads();
#pragma unroll
    for (int i = 0; i < 4; i++)
#pragma unroll
      for (int j = 0; j < 4; j++) sG[(d0 + i) * 64 + e0 + j] = a[i][j];
  }
  __syncthreads();
  for (int i = t; i < 4096; i += 256) sW[i] = Wq[i];
  __syncthreads();
  {
    float a[4][4] = {};
    for (int f = 0; f < 64; f++) {
      float wq[4], t2[4];
      *(float4*)wq = *(const float4*)&sW[f * 64 + d0];
      *(float4*)t2 = *(const float4*)&sG[f * 64 + e0];
#pragma unroll
      for (int i = 0; i < 4; i++)
#pragma unroll
        for (int j = 0; j < 4; j++) a[i][j] = fmaf(wq[i], t2[j], a[i][j]);
    }
#pragma unroll
    for (int i = 0; i < 4; i++)
#pragma unroll
      for (int j = 0; j < 4; j++) sM[(d0 + i) * 64 + e0 + j] = a[i][j] * (1.0f / 8192.0f);
  }
  __syncthreads();
  int dd0 = (t & 15) * 4, cl0 = (t >> 4) * 4;
  for (int cc = qt * 2; cc < qt * 2 + 2; cc++) {
    int c0 = cc * 64;
    for (int i = t; i < 4096; i += 256)
      sW[i] = Wo[(size_t)(c0 + (i >> 6)) * DIMC + h * DH + (i & 63)];
    __syncthreads();
    float a[4][4] = {};
    for (int egi = 0; egi < 16; egi++) {
      int eg = (egi + (t & 15)) & 15;
      float m4[4][4], wo4[4][4];
#pragma unroll
      for (int i = 0; i < 4; i++) *(float4*)m4[i] = *(const float4*)&sM[(dd0 + i) * 64 + eg * 4];
#pragma unroll
      for (int j = 0; j < 4; j++) *(float4*)wo4[j] = *(const float4*)&sW[(cl0 + j) * 64 + eg * 4];
#pragma unroll
      for (int i = 0; i < 4; i++)
#pragma unroll
        for (int j = 0; j < 4; j++)
#pragma unroll
          for (int ff = 0; ff < 4; ff++) a[i][j] = fmaf(m4[i][ff], wo4[j][ff], a[i][j]);
    }
#pragma unroll
    for (int j = 0; j < 4; j++) {
      uint2 pw = {pack_bf2(a[0][j], a[1][j]), pack_bf2(a[2][j], a[3][j])};
      *(uint2*)&WbigT[((size_t)b << 20) + (size_t)(c0 + cl0 + j) * DIMC + h * DH + dd0] = pw;
    }
    __syncthreads();
  }
}

// ---------------- Stage 3a: gemm, fp32-A fallback ---------------------------
__global__ __launch_bounds__(256, 3) void gemm_small(
    const float* __restrict__ x, const short* __restrict__ WbigT,
    const float* __restrict__ bo, float* __restrict__ out) {
  int bid = blockIdx.x;
  int xcd = bid & 7, r = bid >> 3;
  int g = r >> 5, q = r & 31;
  int m_blk = g * 32 + xcd * 4 + (q >> 3);
  int n_blk = q & 7;
  int b = m_blk >> 6;
  int row0 = m_blk * 128;
  int c0 = n_blk * 128;

  __shared__ __align__(16) short As[128 * 32];
  __shared__ __align__(16) short Bs[128 * 32];

  int t = threadIdx.x;
  int lane = t & 63, wave = t >> 6;
  int wm = wave >> 1, wn = wave & 1;
  int quad = lane >> 4, ln = lane & 15;

  f32x4 acc[4][4];
#pragma unroll
  for (int i = 0; i < 4; i++)
#pragma unroll
    for (int j = 0; j < 4; j++) acc[i][j] = (f32x4){0.f, 0.f, 0.f, 0.f};

  const short* Bbase = WbigT + ((size_t)b << 20);

  int e_base[2], crow_[2], lc_[2];
#pragma unroll
  for (int L = 0; L < 2; L++) {
    int e = (wave * 2 + L) * 512 + lane * 8;
    e_base[L] = e;
    int crow = e >> 5;
    crow_[L] = crow;
    lc_[L] = ((e >> 3) & 3) ^ ((crow >> 1) & 3);
  }

  for (int kt = 0; kt < 32; kt++) {
    int k0 = kt * 32;
    __syncthreads();
#pragma unroll
    for (int L = 0; L < 2; L++)
      gload_lds16(Bbase + (size_t)(c0 + crow_[L]) * DIMC + k0 + lc_[L] * 8, &Bs[e_base[L]]);
#pragma unroll
    for (int qq = 0; qq < 2; qq++) {
      int elem = qq * 2048 + wave * 512 + lane * 8;
      int m = elem >> 5, kk = elem & 31;
      const float* gp = x + (size_t)(row0 + m) * DIMC + k0 + kk;
      float4 v0 = *(const float4*)gp;
      float4 v1 = *(const float4*)(gp + 4);
      unsigned w0 = pack_bf2(v0.x, v0.y), w1 = pack_bf2(v0.z, v0.w);
      unsigned w2 = pack_bf2(v1.x, v1.y), w3 = pack_bf2(v1.z, v1.w);
      unsigned tmp[4] = {w0, w1, w2, w3};
      int pe = ((elem >> 3) & 3) ^ ((m >> 1) & 3);
      *(short8*)&As[m * 32 + pe * 8] = *(short8*)tmp;
    }
    __syncthreads();
    short8 afrag[4], bfrag[4];
#pragma unroll
    for (int i = 0; i < 4; i++) {
      int ar = wm * 64 + i * 16 + ln;
      afrag[i] = *(const short8*)&As[ar * 32 + (quad ^ ((ar >> 1) & 3)) * 8];
      int br = wn * 64 + i * 16 + ln;
      bfrag[i] = *(const short8*)&Bs[br * 32 + (quad ^ ((br >> 1) & 3)) * 8];
    }
#pragma unroll
    for (int i = 0; i < 4; i++)
#pragma unroll
      for (int j = 0; j < 4; j++)
        acc[i][j] = __builtin_amdgcn_mfma_f32_16x16x32_bf16(afrag[i], bfrag[j], acc[i][j], 0, 0, 0);
  }

  float bov[4];
#pragma unroll
  for (int j = 0; j < 4; j++) bov[j] = bo[c0 + wn * 64 + j * 16 + ln];
#pragma unroll
  for (int i = 0; i < 4; i++)
#pragma unroll
    for (int j = 0; j < 4; j++) {
      int col = c0 + wn * 64 + j * 16 + ln;
#pragma unroll
      for (int rr = 0; rr < 4; rr++) {
        int row = row0 + wm * 64 + i * 16 + quad * 4 + rr;
        out[(size_t)row * DIMC + col] = acc[i][j][rr] + bov[j];
      }
    }
}

// ---------------- Stage 3b: gemm, bf16-A via DMA (m97 structure, LOCKED) ----
__global__ __launch_bounds__(256, 3) void gemm_big(
    const short* __restrict__ xbf, const short* __restrict__ WbigT,
    const float* __restrict__ bo, float* __restrict__ out) {
  int bid = blockIdx.x;
  int xcd = bid & 7, r = bid >> 3;
  int g = r >> 5, q = r & 31;
  int m_blk = g * 32 + xcd * 4 + (q >> 3);
  int n_blk = q & 7;
  int b = m_blk >> 6;
  int row0 = m_blk * 128;
  int c0 = n_blk * 128;

  __shared__ __align__(16) short As[128 * 32];
  __shared__ __align__(16) short Bs[128 * 32];

  int t = threadIdx.x;
  int lane = t & 63, wave = t >> 6;
  int wm = wave >> 1, wn = wave & 1;
  int quad = lane >> 4, ln = lane & 15;

  f32x4 acc[4][4];
#pragma unroll
  for (int i = 0; i < 4; i++)
#pragma unroll
    for (int j = 0; j < 4; j++) acc[i][j] = (f32x4){0.f, 0.f, 0.f, 0.f};

  const short* Bbase = WbigT + ((size_t)b << 20);

  int e_base[2];
  const short* Asrc[2];
  const short* Bsrc[2];
#pragma unroll
  for (int L = 0; L < 2; L++) {
    int e = (wave * 2 + L) * 512 + lane * 8;
    e_base[L] = e;
    int row = e >> 5;
    int lc = ((e >> 3) & 3) ^ ((row >> 1) & 3);
    Asrc[L] = xbf + (size_t)(row0 + row) * DIMC + lc * 8;
    Bsrc[L] = Bbase + (size_t)(c0 + row) * DIMC + lc * 8;
  }

  for (int kt = 0; kt < 32; kt++) {
    int k0 = kt * 32;
    __syncthreads();
#pragma unroll
    for (int L = 0; L < 2; L++) gload_lds16(Asrc[L] + k0, &As[e_base[L]]);
#pragma unroll
    for (int L = 0; L < 2; L++) gload_lds16(Bsrc[L] + k0, &Bs[e_base[L]]);
    __syncthreads();
    short8 afrag[4], bfrag[4];
#pragma unroll
    for (int i = 0; i < 4; i++) {
      int ar = wm * 64 + i * 16 + ln;
      afrag[i] = *(const short8*)&As[ar * 32 + (quad ^ ((ar >> 1) & 3)) * 8];
      int br = wn * 64 + i * 16 + ln;
      bfrag[i] = *(const short8*)&Bs[br * 32 + (quad ^ ((br >> 1) & 3)) * 8];
    }
#pragma unroll
    for (int i = 0; i < 4; i++)
#pragma unroll
      for (int j = 0; j < 4; j++)
        acc[i][j] = __builtin_amdgcn_mfma_f32_16x16x32_bf16(afrag[i], bfrag[j], acc[i][j], 0, 0, 0);
  }

  float bov[4];
#pragma unroll
  for (int j = 0; j < 4; j++) bov[j] = bo[c0 + wn * 64 + j * 16 + ln];
#pragma unroll
  for (int i = 0; i < 4; i++)
#pragma unroll
    for (int j = 0; j < 4; j++) {
      int col = c0 + wn * 64 + j * 16 + ln;
#pragma unroll
      for (int rr = 0; rr < 4; rr++) {
        int row = row0 + wm * 64 + i * 16 + quad * 4 + rr;
        out[(size_t)row * DIMC + col] = acc[i][j][rr] + bov[j];
      }
    }
}

extern "C" void kernel_launch(void* const* d_in, const int* in_sizes, int n_in,
                              void* d_out, int out_size, void* d_ws, size_t ws_size,
                              hipStream_t stream) {
  const float* x  = (const float*)d_in[0];
  const float* Wq = (const float*)d_in[1];
  const float* Wk = (const float*)d_in[2];
  const float* Wv = (const float*)d_in[3];
  const float* Wo = (const float*)d_in[4];
  const float* bo = (const float*)d_in[5];
  float* out = (float*)d_out;
  (void)in_sizes; (void)n_in; (void)out_size;

  if (ws_size >= ((size_t)81 << 20)) {
    // big path: xbf 64 MiB | Gpart 8 MiB | M 1 MiB | WbigT 8 MiB
    short* xbf   = (short*)d_ws;
    float* Gpart = (float*)((char*)d_ws + ((size_t)64 << 20));
    float* M     = (float*)((char*)d_ws + ((size_t)72 << 20));
    short* WbigT = (short*)((char*)d_ws + ((size_t)73 << 20));
    gram2_kernel<<<dim3(8, 64), 256, 0, stream>>>(x, Gpart, xbf);
    compute_m_kernel<<<64, 256, 0, stream>>>(Gpart, Wq, Wk, Wv, M);
    wbig_kernel<<<dim3(64, 8), 256, 0, stream>>>(M, Wo, WbigT);
    gemm_big<<<2048, 256, 0, stream>>>(xbf, WbigT, bo, out);
  } else {
    // fallback: Gpart 32 MiB | G 1 MiB | WbigT 8 MiB (41 MiB, proven)
    float* Gpart = (float*)d_ws;
    float* G     = (float*)((char*)d_ws + ((size_t)32 << 20));
    short* WbigT = (short*)((char*)d_ws + ((size_t)33 << 20));
    gram_kernel<<<dim3(32, 64), 64, 0, stream>>>(x, Gpart, (short*)0);
    reduce_g<<<1024, 256, 0, stream>>>(Gpart, G, 32);
    combine_kernel<<<dim3(64, 8), 256, 0, stream>>>(G, Wq, Wk, Wv, Wo, WbigT);
    gemm_small<<<2048, 256, 0, stream>>>(x, WbigT, bo, out);
  }
}

// Round 8
// 365.541 us; speedup vs baseline: 1.0061x; 1.0061x over previous
//
#include <hip/hip_runtime.h>

#define DIMC 1024
#define NSEQ 8192
#define DH 64

typedef __attribute__((ext_vector_type(8))) short short8;
typedef __attribute__((ext_vector_type(4))) float f32x4;

__device__ __forceinline__ short f2bf(float f) {
  union { float f; unsigned u; } v; v.f = f;
  unsigned r = v.u + 0x7FFFu + ((v.u >> 16) & 1u);
  return (short)(r >> 16);
}

// pack two fp32 -> two bf16 (lo = a, hi = b); round-half-up, matches bfbits()
__device__ __forceinline__ unsigned pack_bf2(float a, float b) {
  union { float f; unsigned u; } va, vb;
  va.f = a; vb.f = b;
  unsigned ua = va.u + 0x8000u;
  unsigned ub = vb.u + 0x8000u;
  return (ua >> 16) | (ub & 0xFFFF0000u);
}

__device__ __forceinline__ unsigned bfbits(float f) {
  union { float f; unsigned u; } v; v.f = f;
  return (v.u + 0x8000u) >> 16;  // same rounding as pack_bf2
}
__device__ __forceinline__ float bf2f(unsigned hb) {
  union { unsigned u; float f; } v; v.u = hb << 16;
  return v.f;
}

__device__ __forceinline__ void gload_lds16(const void* g, void* l) {
  __builtin_amdgcn_global_load_lds(
      (const __attribute__((address_space(1))) void*)g,
      (__attribute__((address_space(3))) void*)l, 16, 0, 0);
}

// ---------------- Stage 1 (big path): MFMA Gram via hi/lo bf16 split -------
// G = X^T X per (b,h). x = x_hi + x_lo (bf16 each); G ~= H^T H + H^T L + L^T H
// (dropped L^T L ~ 2^-18 relative). Grid (8 chunks, 64 bh), 4 waves.
// In-block LDS reduction of the 4 wave-partials -> 8 global partials.
__global__ __launch_bounds__(256) void gram2_kernel(const float* __restrict__ x,
                                                    float* __restrict__ Gpart,
                                                    short* __restrict__ xbf) {
  int chunk = blockIdx.x, bh = blockIdx.y;
  int b = bh >> 4, h = bh & 15;
  int t = threadIdx.x;
  int w = t >> 6, l = t & 63;
  int quad = l >> 4, ln = l & 15;

  __shared__ __align__(16) short XT[4][2][64 * 32];  // [wave][hi/lo][d][k] 32 KiB
  __shared__ __align__(16) float Pred[3][4096];      // wave 1..3 partials, 48 KiB
  short* XH = &XT[w][0][0];
  short* XL = &XT[w][1][0];

  size_t rowbase = (size_t)b * NSEQ + (size_t)chunk * 1024 + w * 256;
  const float* xb = x + rowbase * DIMC + h * DH;
  short* xo = xbf + rowbase * DIMC + h * DH;

  f32x4 acc[4][4];
#pragma unroll
  for (int i = 0; i < 4; i++)
#pragma unroll
    for (int j = 0; j < 4; j++) acc[i][j] = (f32x4){0.f, 0.f, 0.f, 0.f};

  int woff[4][4];
#pragma unroll
  for (int q = 0; q < 4; q++) {
    int kk = 8 * q + 2 * quad;
    int kp = kk ^ ((ln & 3) << 3);
#pragma unroll
    for (int i = 0; i < 4; i++) {
      int d = ln * 4 + i;
      woff[q][i] = d * 32 + kp;
    }
  }
  int roff[4];
  {
    int k0 = (quad * 8) ^ ((ln >> 2) << 3);
#pragma unroll
    for (int i = 0; i < 4; i++) roff[i] = (i * 16 + ln) * 32 + k0;
  }

  float4 cur[4][2];
#pragma unroll
  for (int q = 0; q < 4; q++)
#pragma unroll
    for (int r = 0; r < 2; r++)
      cur[q][r] = *(const float4*)(xb + (size_t)(8 * q + 2 * quad + r) * DIMC + ln * 4);

  for (int ks = 0; ks < 8; ks++) {
    float4 nxt[4][2];
    if (ks < 7) {
      int nb = (ks + 1) * 32;
#pragma unroll
      for (int q = 0; q < 4; q++)
#pragma unroll
        for (int r = 0; r < 2; r++)
          nxt[q][r] = *(const float4*)(xb + (size_t)(nb + 8 * q + 2 * quad + r) * DIMC + ln * 4);
    }
#pragma unroll
    for (int q = 0; q < 4; q++) {
      unsigned h0[4], h1[4], l0[4], l1[4];
#pragma unroll
      for (int i = 0; i < 4; i++) {
        float a = cur[q][0][i], bb = cur[q][1][i];
        h0[i] = bfbits(a); l0[i] = bfbits(a - bf2f(h0[i]));
        h1[i] = bfbits(bb); l1[i] = bfbits(bb - bf2f(h1[i]));
      }
      int grow = ks * 32 + 8 * q + 2 * quad;
      uint2 p0 = {h0[0] | (h0[1] << 16), h0[2] | (h0[3] << 16)};
      uint2 p1 = {h1[0] | (h1[1] << 16), h1[2] | (h1[3] << 16)};
      *(uint2*)(xo + (size_t)grow * DIMC + ln * 4) = p0;
      *(uint2*)(xo + (size_t)(grow + 1) * DIMC + ln * 4) = p1;
#pragma unroll
      for (int i = 0; i < 4; i++) {
        *(unsigned*)&XH[woff[q][i]] = h0[i] | (h1[i] << 16);
        *(unsigned*)&XL[woff[q][i]] = l0[i] | (l1[i] << 16);
      }
    }
    short8 hf[4], lf[4];
#pragma unroll
    for (int i = 0; i < 4; i++) {
      hf[i] = *(const short8*)&XH[roff[i]];
      lf[i] = *(const short8*)&XL[roff[i]];
    }
#pragma unroll
    for (int i = 0; i < 4; i++)
#pragma unroll
      for (int j = 0; j < 4; j++) {
        acc[i][j] = __builtin_amdgcn_mfma_f32_16x16x32_bf16(hf[i], hf[j], acc[i][j], 0, 0, 0);
        acc[i][j] = __builtin_amdgcn_mfma_f32_16x16x32_bf16(hf[i], lf[j], acc[i][j], 0, 0, 0);
        acc[i][j] = __builtin_amdgcn_mfma_f32_16x16x32_bf16(lf[i], hf[j], acc[i][j], 0, 0, 0);
      }
#pragma unroll
    for (int q = 0; q < 4; q++)
#pragma unroll
      for (int r = 0; r < 2; r++) cur[q][r] = nxt[q][r];
  }

  // in-block reduction: waves 1-3 park partials in LDS, wave 0 merges + stores
  if (w > 0) {
    float* pd = &Pred[w - 1][0];
#pragma unroll
    for (int i = 0; i < 4; i++)
#pragma unroll
      for (int j = 0; j < 4; j++)
#pragma unroll
        for (int r = 0; r < 4; r++) {
          int d = i * 16 + quad * 4 + r, e = j * 16 + ln;
          pd[d * 64 + e] = acc[i][j][r];
        }
  }
  __syncthreads();
  if (w == 0) {
    float* gp = Gpart + (size_t)chunk * (64 * 4096) + (size_t)bh * 4096;
#pragma unroll
    for (int i = 0; i < 4; i++)
#pragma unroll
      for (int j = 0; j < 4; j++)
#pragma unroll
        for (int r = 0; r < 4; r++) {
          int d = i * 16 + quad * 4 + r, e = j * 16 + ln;
          int idx = d * 64 + e;
          gp[idx] = acc[i][j][r] + Pred[0][idx] + Pred[1][idx] + Pred[2][idx];
        }
  }
}

// ---------------- Stage 1 (fallback): fp32 Gram, no xbf ---------------------
__global__ __launch_bounds__(64) void gram_kernel(const float* __restrict__ x,
                                                  float* __restrict__ Gpart,
                                                  short* __restrict__ xbf) {
  int chunk = blockIdx.x, bh = blockIdx.y;
  int b = bh >> 4, h = bh & 15;
  int t = threadIdx.x;
  __shared__ __align__(16) float rows[16 * 64];
  const float* xb = x + ((size_t)b * NSEQ) * DIMC + h * DH;
  short* xo = xbf ? xbf + ((size_t)b * NSEQ) * DIMC + h * DH : (short*)0;
  int d0 = (t >> 3) * 8, e0 = (t & 7) * 8;
  float acc[8][8] = {};
  float4 v[4];
#pragma unroll
  for (int i = 0; i < 4; i++) {
    int f4 = i * 64 + t;
    v[i] = *(const float4*)(xb + (size_t)(chunk * 256 + (f4 >> 4)) * DIMC + (f4 & 15) * 4);
  }
  for (int it = 0; it < 16; it++) {
    __syncthreads();
#pragma unroll
    for (int i = 0; i < 4; i++) ((float4*)rows)[i * 64 + t] = v[i];
    __syncthreads();
    if (xo) {
#pragma unroll
      for (int i = 0; i < 4; i++) {
        int f4 = i * 64 + t;
        int row = chunk * 256 + it * 16 + (f4 >> 4), col = (f4 & 15) * 4;
        uint2 pw = {pack_bf2(v[i].x, v[i].y), pack_bf2(v[i].z, v[i].w)};
        *(uint2*)(xo + (size_t)row * DIMC + col) = pw;
      }
    }
    if (it < 15) {
      int nbase = chunk * 256 + (it + 1) * 16;
#pragma unroll
      for (int i = 0; i < 4; i++) {
        int f4 = i * 64 + t;
        v[i] = *(const float4*)(xb + (size_t)(nbase + (f4 >> 4)) * DIMC + (f4 & 15) * 4);
      }
    }
#pragma unroll
    for (int r = 0; r < 16; r++) {
      float xd[8], xe[8];
      *(float4*)&xd[0] = *(const float4*)&rows[r * 64 + d0];
      *(float4*)&xd[4] = *(const float4*)&rows[r * 64 + d0 + 4];
      *(float4*)&xe[0] = *(const float4*)&rows[r * 64 + e0];
      *(float4*)&xe[4] = *(const float4*)&rows[r * 64 + e0 + 4];
#pragma unroll
      for (int i = 0; i < 8; i++)
#pragma unroll
        for (int j = 0; j < 8; j++) acc[i][j] = fmaf(xd[i], xe[j], acc[i][j]);
    }
  }
  float* gp = Gpart + (size_t)chunk * (64 * 4096) + (size_t)bh * 4096;
#pragma unroll
  for (int i = 0; i < 8; i++)
#pragma unroll
    for (int j = 0; j < 8; j++) gp[(d0 + i) * 64 + e0 + j] = acc[i][j];
}

// ---------------- Stage 1b (fallback only): reduce np partials -> G ---------
__global__ void reduce_g(const float* __restrict__ Gpart, float* __restrict__ G,
                         int np) {
  int i = blockIdx.x * 256 + threadIdx.x;
  float s = 0.f;
  for (int p = 0; p < np; p++) s += Gpart[(size_t)p * (64 * 4096) + i];
  G[i] = s;
}

// ---------------- Stage 2 (big path): combine with inline 8-partial reduce --
// Identical to R6 combine_kernel except sG is built by summing the 8 Gpart
// partials inline (same p-order as reduce_g -> bit-identical). Gpart is
// L2/L3-resident (8 MiB), so the redundant reads across 512 blocks are cheap;
// this deletes the reduce_g launch + G round-trip.
__global__ __launch_bounds__(256) void combine8_kernel(
    const float* __restrict__ Gpart, const float* __restrict__ Wq,
    const float* __restrict__ Wk, const float* __restrict__ Wv,
    const float* __restrict__ Wo, short* __restrict__ WbigT) {
  int bh = blockIdx.x, qt = blockIdx.y;
  int b = bh >> 4, h = bh & 15;
  int t = threadIdx.x;
  __shared__ __align__(16) float sG[4096];
  __shared__ __align__(16) float sW[4096];
  __shared__ __align__(16) float sA[4096];
  __shared__ __align__(16) float sM[4096];

  for (int i = t; i < 4096; i += 256) {
    float s = 0.f;
#pragma unroll
    for (int p = 0; p < 8; p++)
      s += Gpart[(size_t)p * (64 * 4096) + (size_t)bh * 4096 + i];
    sG[i] = s;
  }
  for (int i = t; i < 4096; i += 256) sW[i] = Wk[i];
  __syncthreads();

  int d0 = (t >> 4) * 4, e0 = (t & 15) * 4;
  // T1 = Wk * G -> sA
  {
    float a[4][4] = {};
    for (int fg = 0; fg < 16; fg++) {
      float wk[4][4], g4[4][4];
#pragma unroll
      for (int i = 0; i < 4; i++) *(float4*)wk[i] = *(const float4*)&sW[(d0 + i) * 64 + fg * 4];
#pragma unroll
      for (int ff = 0; ff < 4; ff++) *(float4*)g4[ff] = *(const float4*)&sG[(fg * 4 + ff) * 64 + e0];
#pragma unroll
      for (int i = 0; i < 4; i++)
#pragma unroll
        for (int ff = 0; ff < 4; ff++)
#pragma unroll
          for (int j = 0; j < 4; j++) a[i][j] = fmaf(wk[i][ff], g4[ff][j], a[i][j]);
    }
#pragma unroll
    for (int i = 0; i < 4; i++)
#pragma unroll
      for (int j = 0; j < 4; j++) sA[(d0 + i) * 64 + e0 + j] = a[i][j];
  }
  __syncthreads();
  for (int i = t; i < 4096; i += 256) sW[i] = Wv[i];
  __syncthreads();
  // T2 = T1 * Wv^T -> sG
  {
    float a[4][4] = {};
    for (int fgi = 0; fgi < 16; fgi++) {
      int fg = (fgi + (t & 15)) & 15;
      float t1[4][4], wv[4][4];
#pragma unroll
      for (int i = 0; i < 4; i++) *(float4*)t1[i] = *(const float4*)&sA[(d0 + i) * 64 + fg * 4];
#pragma unroll
      for (int j = 0; j < 4; j++) *(float4*)wv[j] = *(const float4*)&sW[(e0 + j) * 64 + fg * 4];
#pragma unroll
      for (int i = 0; i < 4; i++)
#pragma unroll
        for (int j = 0; j < 4; j++)
#pragma unroll
          for (int ff = 0; ff < 4; ff++) a[i][j] = fmaf(t1[i][ff], wv[j][ff], a[i][j]);
    }
    __syncthreads();
#pragma unroll
    for (int i = 0; i < 4; i++)
#pragma unroll
      for (int j = 0; j < 4; j++) sG[(d0 + i) * 64 + e0 + j] = a[i][j];
  }
  __syncthreads();
  for (int i = t; i < 4096; i += 256) sW[i] = Wq[i];
  __syncthreads();
  // M = Wq^T * T2 / N -> sM
  {
    float a[4][4] = {};
    for (int f = 0; f < 64; f++) {
      float wq[4], t2[4];
      *(float4*)wq = *(const float4*)&sW[f * 64 + d0];
      *(float4*)t2 = *(const float4*)&sG[f * 64 + e0];
#pragma unroll
      for (int i = 0; i < 4; i++)
#pragma unroll
        for (int j = 0; j < 4; j++) a[i][j] = fmaf(wq[i], t2[j], a[i][j]);
    }
#pragma unroll
    for (int i = 0; i < 4; i++)
#pragma unroll
      for (int j = 0; j < 4; j++) sM[(d0 + i) * 64 + e0 + j] = a[i][j] * (1.0f / 8192.0f);
  }
  __syncthreads();
  int dd0 = (t & 15) * 4, cl0 = (t >> 4) * 4;
  for (int cc = qt * 2; cc < qt * 2 + 2; cc++) {
    int c0 = cc * 64;
    for (int i = t; i < 4096; i += 256)
      sW[i] = Wo[(size_t)(c0 + (i >> 6)) * DIMC + h * DH + (i & 63)];
    __syncthreads();
    float a[4][4] = {};
    for (int egi = 0; egi < 16; egi++) {
      int eg = (egi + (t & 15)) & 15;
      float m4[4][4], wo4[4][4];
#pragma unroll
      for (int i = 0; i < 4; i++) *(float4*)m4[i] = *(const float4*)&sM[(dd0 + i) * 64 + eg * 4];
#pragma unroll
      for (int j = 0; j < 4; j++) *(float4*)wo4[j] = *(const float4*)&sW[(cl0 + j) * 64 + eg * 4];
#pragma unroll
      for (int i = 0; i < 4; i++)
#pragma unroll
        for (int j = 0; j < 4; j++)
#pragma unroll
          for (int ff = 0; ff < 4; ff++) a[i][j] = fmaf(m4[i][ff], wo4[j][ff], a[i][j]);
    }
#pragma unroll
    for (int j = 0; j < 4; j++) {
      uint2 pw = {pack_bf2(a[0][j], a[1][j]), pack_bf2(a[2][j], a[3][j])};
      *(uint2*)&WbigT[((size_t)b << 20) + (size_t)(c0 + cl0 + j) * DIMC + h * DH + dd0] = pw;
    }
    __syncthreads();
  }
}

// ---------------- Stage 2 (fallback): original fused combine ----------------
__global__ __launch_bounds__(256) void combine_kernel(
    const float* __restrict__ G, const float* __restrict__ Wq,
    const float* __restrict__ Wk, const float* __restrict__ Wv,
    const float* __restrict__ Wo, short* __restrict__ WbigT) {
  int bh = blockIdx.x, qt = blockIdx.y;
  int b = bh >> 4, h = bh & 15;
  int t = threadIdx.x;
  __shared__ __align__(16) float sG[4096];
  __shared__ __align__(16) float sW[4096];
  __shared__ __align__(16) float sA[4096];
  __shared__ __align__(16) float sM[4096];

  for (int i = t; i < 4096; i += 256) sG[i] = G[(size_t)bh * 4096 + i];
  for (int i = t; i < 4096; i += 256) sW[i] = Wk[i];
  __syncthreads();

  int d0 = (t >> 4) * 4, e0 = (t & 15) * 4;
  {
    float a[4][4] = {};
    for (int fg = 0; fg < 16; fg++) {
      float wk[4][4], g4[4][4];
#pragma unroll
      for (int i = 0; i < 4; i++) *(float4*)wk[i] = *(const float4*)&sW[(d0 + i) * 64 + fg * 4];
#pragma unroll
      for (int ff = 0; ff < 4; ff++) *(float4*)g4[ff] = *(const float4*)&sG[(fg * 4 + ff) * 64 + e0];
#pragma unroll
      for (int i = 0; i < 4; i++)
#pragma unroll
        for (int ff = 0; ff < 4; ff++)
#pragma unroll
          for (int j = 0; j < 4; j++) a[i][j] = fmaf(wk[i][ff], g4[ff][j], a[i][j]);
    }
#pragma unroll
    for (int i = 0; i < 4; i++)
#pragma unroll
      for (int j = 0; j < 4; j++) sA[(d0 + i) * 64 + e0 + j] = a[i][j];
  }
  __syncthreads();
  for (int i = t; i < 4096; i += 256) sW[i] = Wv[i];
  __syncthreads();
  {
    float a[4][4] = {};
    for (int fgi = 0; fgi < 16; fgi++) {
      int fg = (fgi + (t & 15)) & 15;
      float t1[4][4], wv[4][4];
#pragma unroll
      for (int i = 0; i < 4; i++) *(float4*)t1[i] = *(const float4*)&sA[(d0 + i) * 64 + fg * 4];
#pragma unroll
      for (int j = 0; j < 4; j++) *(float4*)wv[j] = *(const float4*)&sW[(e0 + j) * 64 + fg * 4];
#pragma unroll
      for (int i = 0; i < 4; i++)
#pragma unroll
        for (int j = 0; j < 4; j++)
#pragma unroll
          for (int ff = 0; ff < 4; ff++) a[i][j] = fmaf(t1[i][ff], wv[j][ff], a[i][j]);
    }
    __syncthreads();
#pragma unroll
    for (int i = 0; i < 4; i++)
#pragma unroll
      for (int j = 0; j < 4; j++) sG[(d0 + i) * 64 + e0 + j] = a[i][j];
  }
  __syncthreads();
  for (int i = t; i < 4096; i += 256) sW[i] = Wq[i];
  __syncthreads();
  {
    float a[4][4] = {};
    for (int f = 0; f < 64; f++) {
      float wq[4], t2[4];
      *(float4*)wq = *(const float4*)&sW[f * 64 + d0];
      *(float4*)t2 = *(const float4*)&sG[f * 64 + e0];
#pragma unroll
      for (int i = 0; i < 4; i++)
#pragma unroll
        for (int j = 0; j < 4; j++) a[i][j] = fmaf(wq[i], t2[j], a[i][j]);
    }
#pragma unroll
    for (int i = 0; i < 4; i++)
#pragma unroll
      for (int j = 0; j < 4; j++) sM[(d0 + i) * 64 + e0 + j] = a[i][j] * (1.0f / 8192.0f);
  }
  __syncthreads();
  int dd0 = (t & 15) * 4, cl0 = (t >> 4) * 4;
  for (int cc = qt * 2; cc < qt * 2 + 2; cc++) {
    int c0 = cc * 64;
    for (int i = t; i < 4096; i += 256)
      sW[i] = Wo[(size_t)(c0 + (i >> 6)) * DIMC + h * DH + (i & 63)];
    __syncthreads();
    float a[4][4] = {};
    for (int egi = 0; egi < 16; egi++) {
      int eg = (egi + (t & 15)) & 15;
      float m4[4][4], wo4[4][4];
#pragma unroll
      for (int i = 0; i < 4; i++) *(float4*)m4[i] = *(const float4*)&sM[(dd0 + i) * 64 + eg * 4];
#pragma unroll
      for (int j = 0; j < 4; j++) *(float4*)wo4[j] = *(const float4*)&sW[(cl0 + j) * 64 + eg * 4];
#pragma unroll
      for (int i = 0; i < 4; i++)
#pragma unroll
        for (int j = 0; j < 4; j++)
#pragma unroll
          for (int ff = 0; ff < 4; ff++) a[i][j] = fmaf(m4[i][ff], wo4[j][ff], a[i][j]);
    }
#pragma unroll
    for (int j = 0; j < 4; j++) {
      uint2 pw = {pack_bf2(a[0][j], a[1][j]), pack_bf2(a[2][j], a[3][j])};
      *(uint2*)&WbigT[((size_t)b << 20) + (size_t)(c0 + cl0 + j) * DIMC + h * DH + dd0] = pw;
    }
    __syncthreads();
  }
}

// ---------------- Stage 3a: gemm, fp32-A fallback ---------------------------
__global__ __launch_bounds__(256, 3) void gemm_small(
    const float* __restrict__ x, const short* __restrict__ WbigT,
    const float* __restrict__ bo, float* __restrict__ out) {
  int bid = blockIdx.x;
  int xcd = bid & 7, r = bid >> 3;
  int g = r >> 5, q = r & 31;
  int m_blk = g * 32 + xcd * 4 + (q >> 3);
  int n_blk = q & 7;
  int b = m_blk >> 6;
  int row0 = m_blk * 128;
  int c0 = n_blk * 128;

  __shared__ __align__(16) short As[128 * 32];
  __shared__ __align__(16) short Bs[128 * 32];

  int t = threadIdx.x;
  int lane = t & 63, wave = t >> 6;
  int wm = wave >> 1, wn = wave & 1;
  int quad = lane >> 4, ln = lane & 15;

  f32x4 acc[4][4];
#pragma unroll
  for (int i = 0; i < 4; i++)
#pragma unroll
    for (int j = 0; j < 4; j++) acc[i][j] = (f32x4){0.f, 0.f, 0.f, 0.f};

  const short* Bbase = WbigT + ((size_t)b << 20);

  int e_base[2], crow_[2], lc_[2];
#pragma unroll
  for (int L = 0; L < 2; L++) {
    int e = (wave * 2 + L) * 512 + lane * 8;
    e_base[L] = e;
    int crow = e >> 5;
    crow_[L] = crow;
    lc_[L] = ((e >> 3) & 3) ^ ((crow >> 1) & 3);
  }

  for (int kt = 0; kt < 32; kt++) {
    int k0 = kt * 32;
    __syncthreads();
#pragma unroll
    for (int L = 0; L < 2; L++)
      gload_lds16(Bbase + (size_t)(c0 + crow_[L]) * DIMC + k0 + lc_[L] * 8, &Bs[e_base[L]]);
#pragma unroll
    for (int qq = 0; qq < 2; qq++) {
      int elem = qq * 2048 + wave * 512 + lane * 8;
      int m = elem >> 5, kk = elem & 31;
      const float* gp = x + (size_t)(row0 + m) * DIMC + k0 + kk;
      float4 v0 = *(const float4*)gp;
      float4 v1 = *(const float4*)(gp + 4);
      unsigned w0 = pack_bf2(v0.x, v0.y), w1 = pack_bf2(v0.z, v0.w);
      unsigned w2 = pack_bf2(v1.x, v1.y), w3 = pack_bf2(v1.z, v1.w);
      unsigned tmp[4] = {w0, w1, w2, w3};
      int pe = ((elem >> 3) & 3) ^ ((m >> 1) & 3);
      *(short8*)&As[m * 32 + pe * 8] = *(short8*)tmp;
    }
    __syncthreads();
    short8 afrag[4], bfrag[4];
#pragma unroll
    for (int i = 0; i < 4; i++) {
      int ar = wm * 64 + i * 16 + ln;
      afrag[i] = *(const short8*)&As[ar * 32 + (quad ^ ((ar >> 1) & 3)) * 8];
      int br = wn * 64 + i * 16 + ln;
      bfrag[i] = *(const short8*)&Bs[br * 32 + (quad ^ ((br >> 1) & 3)) * 8];
    }
#pragma unroll
    for (int i = 0; i < 4; i++)
#pragma unroll
      for (int j = 0; j < 4; j++)
        acc[i][j] = __builtin_amdgcn_mfma_f32_16x16x32_bf16(afrag[i], bfrag[j], acc[i][j], 0, 0, 0);
  }

  float bov[4];
#pragma unroll
  for (int j = 0; j < 4; j++) bov[j] = bo[c0 + wn * 64 + j * 16 + ln];
#pragma unroll
  for (int i = 0; i < 4; i++)
#pragma unroll
    for (int j = 0; j < 4; j++) {
      int col = c0 + wn * 64 + j * 16 + ln;
#pragma unroll
      for (int rr = 0; rr < 4; rr++) {
        int row = row0 + wm * 64 + i * 16 + quad * 4 + rr;
        out[(size_t)row * DIMC + col] = acc[i][j][rr] + bov[j];
      }
    }
}

// ---------------- Stage 3b: gemm, bf16-A via DMA (m97 structure, LOCKED) ----
__global__ __launch_bounds__(256, 3) void gemm_big(
    const short* __restrict__ xbf, const short* __restrict__ WbigT,
    const float* __restrict__ bo, float* __restrict__ out) {
  int bid = blockIdx.x;
  int xcd = bid & 7, r = bid >> 3;
  int g = r >> 5, q = r & 31;
  int m_blk = g * 32 + xcd * 4 + (q >> 3);
  int n_blk = q & 7;
  int b = m_blk >> 6;
  int row0 = m_blk * 128;
  int c0 = n_blk * 128;

  __shared__ __align__(16) short As[128 * 32];
  __shared__ __align__(16) short Bs[128 * 32];

  int t = threadIdx.x;
  int lane = t & 63, wave = t >> 6;
  int wm = wave >> 1, wn = wave & 1;
  int quad = lane >> 4, ln = lane & 15;

  f32x4 acc[4][4];
#pragma unroll
  for (int i = 0; i < 4; i++)
#pragma unroll
    for (int j = 0; j < 4; j++) acc[i][j] = (f32x4){0.f, 0.f, 0.f, 0.f};

  const short* Bbase = WbigT + ((size_t)b << 20);

  int e_base[2];
  const short* Asrc[2];
  const short* Bsrc[2];
#pragma unroll
  for (int L = 0; L < 2; L++) {
    int e = (wave * 2 + L) * 512 + lane * 8;
    e_base[L] = e;
    int row = e >> 5;
    int lc = ((e >> 3) & 3) ^ ((row >> 1) & 3);
    Asrc[L] = xbf + (size_t)(row0 + row) * DIMC + lc * 8;
    Bsrc[L] = Bbase + (size_t)(c0 + row) * DIMC + lc * 8;
  }

  for (int kt = 0; kt < 32; kt++) {
    int k0 = kt * 32;
    __syncthreads();
#pragma unroll
    for (int L = 0; L < 2; L++) gload_lds16(Asrc[L] + k0, &As[e_base[L]]);
#pragma unroll
    for (int L = 0; L < 2; L++) gload_lds16(Bsrc[L] + k0, &Bs[e_base[L]]);
    __syncthreads();
    short8 afrag[4], bfrag[4];
#pragma unroll
    for (int i = 0; i < 4; i++) {
      int ar = wm * 64 + i * 16 + ln;
      afrag[i] = *(const short8*)&As[ar * 32 + (quad ^ ((ar >> 1) & 3)) * 8];
      int br = wn * 64 + i * 16 + ln;
      bfrag[i] = *(const short8*)&Bs[br * 32 + (quad ^ ((br >> 1) & 3)) * 8];
    }
#pragma unroll
    for (int i = 0; i < 4; i++)
#pragma unroll
      for (int j = 0; j < 4; j++)
        acc[i][j] = __builtin_amdgcn_mfma_f32_16x16x32_bf16(afrag[i], bfrag[j], acc[i][j], 0, 0, 0);
  }

  float bov[4];
#pragma unroll
  for (int j = 0; j < 4; j++) bov[j] = bo[c0 + wn * 64 + j * 16 + ln];
#pragma unroll
  for (int i = 0; i < 4; i++)
#pragma unroll
    for (int j = 0; j < 4; j++) {
      int col = c0 + wn * 64 + j * 16 + ln;
#pragma unroll
      for (int rr = 0; rr < 4; rr++) {
        int row = row0 + wm * 64 + i * 16 + quad * 4 + rr;
        out[(size_t)row * DIMC + col] = acc[i][j][rr] + bov[j];
      }
    }
}

extern "C" void kernel_launch(void* const* d_in, const int* in_sizes, int n_in,
                              void* d_out, int out_size, void* d_ws, size_t ws_size,
                              hipStream_t stream) {
  const float* x  = (const float*)d_in[0];
  const float* Wq = (const float*)d_in[1];
  const float* Wk = (const float*)d_in[2];
  const float* Wv = (const float*)d_in[3];
  const float* Wo = (const float*)d_in[4];
  const float* bo = (const float*)d_in[5];
  float* out = (float*)d_out;
  (void)in_sizes; (void)n_in; (void)out_size;

  if (ws_size >= ((size_t)81 << 20)) {
    // big path: xbf 64 MiB | Gpart 8 MiB | WbigT 8 MiB (3 launches)
    short* xbf   = (short*)d_ws;
    float* Gpart = (float*)((char*)d_ws + ((size_t)64 << 20));
    short* WbigT = (short*)((char*)d_ws + ((size_t)72 << 20));
    gram2_kernel<<<dim3(8, 64), 256, 0, stream>>>(x, Gpart, xbf);
    combine8_kernel<<<dim3(64, 8), 256, 0, stream>>>(Gpart, Wq, Wk, Wv, Wo, WbigT);
    gemm_big<<<2048, 256, 0, stream>>>(xbf, WbigT, bo, out);
  } else {
    // fallback: Gpart 32 MiB | G 1 MiB | WbigT 8 MiB (41 MiB, proven)
    float* Gpart = (float*)d_ws;
    float* G     = (float*)((char*)d_ws + ((size_t)32 << 20));
    short* WbigT = (short*)((char*)d_ws + ((size_t)33 << 20));
    gram_kernel<<<dim3(32, 64), 64, 0, stream>>>(x, Gpart, (short*)0);
    reduce_g<<<1024, 256, 0, stream>>>(Gpart, G, 32);
    combine_kernel<<<dim3(64, 8), 256, 0, stream>>>(G, Wq, Wk, Wv, Wo, WbigT);
    gemm_small<<<2048, 256, 0, stream>>>(x, WbigT, bo, out);
  }
}

// Round 9
// 357.228 us; speedup vs baseline: 1.0295x; 1.0233x over previous
//
#include <hip/hip_runtime.h>

#define DIMC 1024
#define NSEQ 8192
#define DH 64

typedef __attribute__((ext_vector_type(8))) short short8;
typedef __attribute__((ext_vector_type(4))) float f32x4;

__device__ __forceinline__ short f2bf(float f) {
  union { float f; unsigned u; } v; v.f = f;
  unsigned r = v.u + 0x7FFFu + ((v.u >> 16) & 1u);
  return (short)(r >> 16);
}

// pack two fp32 -> two bf16 (lo = a, hi = b); round-half-up, matches bfbits()
__device__ __forceinline__ unsigned pack_bf2(float a, float b) {
  union { float f; unsigned u; } va, vb;
  va.f = a; vb.f = b;
  unsigned ua = va.u + 0x8000u;
  unsigned ub = vb.u + 0x8000u;
  return (ua >> 16) | (ub & 0xFFFF0000u);
}

__device__ __forceinline__ unsigned bfbits(float f) {
  union { float f; unsigned u; } v; v.f = f;
  return (v.u + 0x8000u) >> 16;  // same rounding as pack_bf2
}
__device__ __forceinline__ float bf2f(unsigned hb) {
  union { unsigned u; float f; } v; v.u = hb << 16;
  return v.f;
}

__device__ __forceinline__ void gload_lds16(const void* g, void* l) {
  __builtin_amdgcn_global_load_lds(
      (const __attribute__((address_space(1))) void*)g,
      (__attribute__((address_space(3))) void*)l, 16, 0, 0);
}

// ---------------- Stage 1 (big path): MFMA Gram via hi/lo bf16 split -------
// G = X^T X per (b,h). x = x_hi + x_lo (bf16 each); G ~= H^T H + H^T L + L^T H
// (dropped L^T L ~ 2^-18 relative). Grid (8 chunks, 64 bh), 4 waves.
// In-block LDS reduction of the 4 wave-partials -> 8 global partials.
__global__ __launch_bounds__(256) void gram2_kernel(const float* __restrict__ x,
                                                    float* __restrict__ Gpart,
                                                    short* __restrict__ xbf) {
  int chunk = blockIdx.x, bh = blockIdx.y;
  int b = bh >> 4, h = bh & 15;
  int t = threadIdx.x;
  int w = t >> 6, l = t & 63;
  int quad = l >> 4, ln = l & 15;

  __shared__ __align__(16) short XT[4][2][64 * 32];  // [wave][hi/lo][d][k] 32 KiB
  __shared__ __align__(16) float Pred[3][4096];      // wave 1..3 partials, 48 KiB
  short* XH = &XT[w][0][0];
  short* XL = &XT[w][1][0];

  size_t rowbase = (size_t)b * NSEQ + (size_t)chunk * 1024 + w * 256;
  const float* xb = x + rowbase * DIMC + h * DH;
  short* xo = xbf + rowbase * DIMC + h * DH;

  f32x4 acc[4][4];
#pragma unroll
  for (int i = 0; i < 4; i++)
#pragma unroll
    for (int j = 0; j < 4; j++) acc[i][j] = (f32x4){0.f, 0.f, 0.f, 0.f};

  int woff[4][4];
#pragma unroll
  for (int q = 0; q < 4; q++) {
    int kk = 8 * q + 2 * quad;
    int kp = kk ^ ((ln & 3) << 3);
#pragma unroll
    for (int i = 0; i < 4; i++) {
      int d = ln * 4 + i;
      woff[q][i] = d * 32 + kp;
    }
  }
  int roff[4];
  {
    int k0 = (quad * 8) ^ ((ln >> 2) << 3);
#pragma unroll
    for (int i = 0; i < 4; i++) roff[i] = (i * 16 + ln) * 32 + k0;
  }

  float4 cur[4][2];
#pragma unroll
  for (int q = 0; q < 4; q++)
#pragma unroll
    for (int r = 0; r < 2; r++)
      cur[q][r] = *(const float4*)(xb + (size_t)(8 * q + 2 * quad + r) * DIMC + ln * 4);

  for (int ks = 0; ks < 8; ks++) {
    float4 nxt[4][2];
    if (ks < 7) {
      int nb = (ks + 1) * 32;
#pragma unroll
      for (int q = 0; q < 4; q++)
#pragma unroll
        for (int r = 0; r < 2; r++)
          nxt[q][r] = *(const float4*)(xb + (size_t)(nb + 8 * q + 2 * quad + r) * DIMC + ln * 4);
    }
#pragma unroll
    for (int q = 0; q < 4; q++) {
      unsigned h0[4], h1[4], l0[4], l1[4];
#pragma unroll
      for (int i = 0; i < 4; i++) {
        float a = cur[q][0][i], bb = cur[q][1][i];
        h0[i] = bfbits(a); l0[i] = bfbits(a - bf2f(h0[i]));
        h1[i] = bfbits(bb); l1[i] = bfbits(bb - bf2f(h1[i]));
      }
      int grow = ks * 32 + 8 * q + 2 * quad;
      uint2 p0 = {h0[0] | (h0[1] << 16), h0[2] | (h0[3] << 16)};
      uint2 p1 = {h1[0] | (h1[1] << 16), h1[2] | (h1[3] << 16)};
      *(uint2*)(xo + (size_t)grow * DIMC + ln * 4) = p0;
      *(uint2*)(xo + (size_t)(grow + 1) * DIMC + ln * 4) = p1;
#pragma unroll
      for (int i = 0; i < 4; i++) {
        *(unsigned*)&XH[woff[q][i]] = h0[i] | (h1[i] << 16);
        *(unsigned*)&XL[woff[q][i]] = l0[i] | (l1[i] << 16);
      }
    }
    short8 hf[4], lf[4];
#pragma unroll
    for (int i = 0; i < 4; i++) {
      hf[i] = *(const short8*)&XH[roff[i]];
      lf[i] = *(const short8*)&XL[roff[i]];
    }
#pragma unroll
    for (int i = 0; i < 4; i++)
#pragma unroll
      for (int j = 0; j < 4; j++) {
        acc[i][j] = __builtin_amdgcn_mfma_f32_16x16x32_bf16(hf[i], hf[j], acc[i][j], 0, 0, 0);
        acc[i][j] = __builtin_amdgcn_mfma_f32_16x16x32_bf16(hf[i], lf[j], acc[i][j], 0, 0, 0);
        acc[i][j] = __builtin_amdgcn_mfma_f32_16x16x32_bf16(lf[i], hf[j], acc[i][j], 0, 0, 0);
      }
#pragma unroll
    for (int q = 0; q < 4; q++)
#pragma unroll
      for (int r = 0; r < 2; r++) cur[q][r] = nxt[q][r];
  }

  // in-block reduction: waves 1-3 park partials in LDS, wave 0 merges + stores
  if (w > 0) {
    float* pd = &Pred[w - 1][0];
#pragma unroll
    for (int i = 0; i < 4; i++)
#pragma unroll
      for (int j = 0; j < 4; j++)
#pragma unroll
        for (int r = 0; r < 4; r++) {
          int d = i * 16 + quad * 4 + r, e = j * 16 + ln;
          pd[d * 64 + e] = acc[i][j][r];
        }
  }
  __syncthreads();
  if (w == 0) {
    float* gp = Gpart + (size_t)chunk * (64 * 4096) + (size_t)bh * 4096;
#pragma unroll
    for (int i = 0; i < 4; i++)
#pragma unroll
      for (int j = 0; j < 4; j++)
#pragma unroll
        for (int r = 0; r < 4; r++) {
          int d = i * 16 + quad * 4 + r, e = j * 16 + ln;
          int idx = d * 64 + e;
          gp[idx] = acc[i][j][r] + Pred[0][idx] + Pred[1][idx] + Pred[2][idx];
        }
  }
}

// ---------------- Stage 1 (fallback): fp32 Gram, no xbf ---------------------
__global__ __launch_bounds__(64) void gram_kernel(const float* __restrict__ x,
                                                  float* __restrict__ Gpart,
                                                  short* __restrict__ xbf) {
  int chunk = blockIdx.x, bh = blockIdx.y;
  int b = bh >> 4, h = bh & 15;
  int t = threadIdx.x;
  __shared__ __align__(16) float rows[16 * 64];
  const float* xb = x + ((size_t)b * NSEQ) * DIMC + h * DH;
  short* xo = xbf ? xbf + ((size_t)b * NSEQ) * DIMC + h * DH : (short*)0;
  int d0 = (t >> 3) * 8, e0 = (t & 7) * 8;
  float acc[8][8] = {};
  float4 v[4];
#pragma unroll
  for (int i = 0; i < 4; i++) {
    int f4 = i * 64 + t;
    v[i] = *(const float4*)(xb + (size_t)(chunk * 256 + (f4 >> 4)) * DIMC + (f4 & 15) * 4);
  }
  for (int it = 0; it < 16; it++) {
    __syncthreads();
#pragma unroll
    for (int i = 0; i < 4; i++) ((float4*)rows)[i * 64 + t] = v[i];
    __syncthreads();
    if (xo) {
#pragma unroll
      for (int i = 0; i < 4; i++) {
        int f4 = i * 64 + t;
        int row = chunk * 256 + it * 16 + (f4 >> 4), col = (f4 & 15) * 4;
        uint2 pw = {pack_bf2(v[i].x, v[i].y), pack_bf2(v[i].z, v[i].w)};
        *(uint2*)(xo + (size_t)row * DIMC + col) = pw;
      }
    }
    if (it < 15) {
      int nbase = chunk * 256 + (it + 1) * 16;
#pragma unroll
      for (int i = 0; i < 4; i++) {
        int f4 = i * 64 + t;
        v[i] = *(const float4*)(xb + (size_t)(nbase + (f4 >> 4)) * DIMC + (f4 & 15) * 4);
      }
    }
#pragma unroll
    for (int r = 0; r < 16; r++) {
      float xd[8], xe[8];
      *(float4*)&xd[0] = *(const float4*)&rows[r * 64 + d0];
      *(float4*)&xd[4] = *(const float4*)&rows[r * 64 + d0 + 4];
      *(float4*)&xe[0] = *(const float4*)&rows[r * 64 + e0];
      *(float4*)&xe[4] = *(const float4*)&rows[r * 64 + e0 + 4];
#pragma unroll
      for (int i = 0; i < 8; i++)
#pragma unroll
        for (int j = 0; j < 8; j++) acc[i][j] = fmaf(xd[i], xe[j], acc[i][j]);
    }
  }
  float* gp = Gpart + (size_t)chunk * (64 * 4096) + (size_t)bh * 4096;
#pragma unroll
  for (int i = 0; i < 8; i++)
#pragma unroll
    for (int j = 0; j < 8; j++) gp[(d0 + i) * 64 + e0 + j] = acc[i][j];
}

// ---------------- Stage 1b: reduce np partials -> G ----------
__global__ void reduce_g(const float* __restrict__ Gpart, float* __restrict__ G,
                         int np) {
  int i = blockIdx.x * 256 + threadIdx.x;
  float s = 0.f;
  for (int p = 0; p < np; p++) s += Gpart[(size_t)p * (64 * 4096) + i];
  G[i] = s;
}

// ---------------- Stage 2: WbigT[b][c][k] (R6-proven fused combine) ---------
__global__ __launch_bounds__(256) void combine_kernel(
    const float* __restrict__ G, const float* __restrict__ Wq,
    const float* __restrict__ Wk, const float* __restrict__ Wv,
    const float* __restrict__ Wo, short* __restrict__ WbigT) {
  int bh = blockIdx.x, qt = blockIdx.y;
  int b = bh >> 4, h = bh & 15;
  int t = threadIdx.x;
  __shared__ __align__(16) float sG[4096];
  __shared__ __align__(16) float sW[4096];
  __shared__ __align__(16) float sA[4096];
  __shared__ __align__(16) float sM[4096];

  for (int i = t; i < 4096; i += 256) sG[i] = G[(size_t)bh * 4096 + i];
  for (int i = t; i < 4096; i += 256) sW[i] = Wk[i];
  __syncthreads();

  int d0 = (t >> 4) * 4, e0 = (t & 15) * 4;
  // T1 = Wk * G -> sA
  {
    float a[4][4] = {};
    for (int fg = 0; fg < 16; fg++) {
      float wk[4][4], g4[4][4];
#pragma unroll
      for (int i = 0; i < 4; i++) *(float4*)wk[i] = *(const float4*)&sW[(d0 + i) * 64 + fg * 4];
#pragma unroll
      for (int ff = 0; ff < 4; ff++) *(float4*)g4[ff] = *(const float4*)&sG[(fg * 4 + ff) * 64 + e0];
#pragma unroll
      for (int i = 0; i < 4; i++)
#pragma unroll
        for (int ff = 0; ff < 4; ff++)
#pragma unroll
          for (int j = 0; j < 4; j++) a[i][j] = fmaf(wk[i][ff], g4[ff][j], a[i][j]);
    }
#pragma unroll
    for (int i = 0; i < 4; i++)
#pragma unroll
      for (int j = 0; j < 4; j++) sA[(d0 + i) * 64 + e0 + j] = a[i][j];
  }
  __syncthreads();
  for (int i = t; i < 4096; i += 256) sW[i] = Wv[i];
  __syncthreads();
  // T2 = T1 * Wv^T -> sG
  {
    float a[4][4] = {};
    for (int fgi = 0; fgi < 16; fgi++) {
      int fg = (fgi + (t & 15)) & 15;
      float t1[4][4], wv[4][4];
#pragma unroll
      for (int i = 0; i < 4; i++) *(float4*)t1[i] = *(const float4*)&sA[(d0 + i) * 64 + fg * 4];
#pragma unroll
      for (int j = 0; j < 4; j++) *(float4*)wv[j] = *(const float4*)&sW[(e0 + j) * 64 + fg * 4];
#pragma unroll
      for (int i = 0; i < 4; i++)
#pragma unroll
        for (int j = 0; j < 4; j++)
#pragma unroll
          for (int ff = 0; ff < 4; ff++) a[i][j] = fmaf(t1[i][ff], wv[j][ff], a[i][j]);
    }
    __syncthreads();
#pragma unroll
    for (int i = 0; i < 4; i++)
#pragma unroll
      for (int j = 0; j < 4; j++) sG[(d0 + i) * 64 + e0 + j] = a[i][j];
  }
  __syncthreads();
  for (int i = t; i < 4096; i += 256) sW[i] = Wq[i];
  __syncthreads();
  // M = Wq^T * T2 / N -> sM
  {
    float a[4][4] = {};
    for (int f = 0; f < 64; f++) {
      float wq[4], t2[4];
      *(float4*)wq = *(const float4*)&sW[f * 64 + d0];
      *(float4*)t2 = *(const float4*)&sG[f * 64 + e0];
#pragma unroll
      for (int i = 0; i < 4; i++)
#pragma unroll
        for (int j = 0; j < 4; j++) a[i][j] = fmaf(wq[i], t2[j], a[i][j]);
    }
#pragma unroll
    for (int i = 0; i < 4; i++)
#pragma unroll
      for (int j = 0; j < 4; j++) sM[(d0 + i) * 64 + e0 + j] = a[i][j] * (1.0f / 8192.0f);
  }
  __syncthreads();
  int dd0 = (t & 15) * 4, cl0 = (t >> 4) * 4;
  for (int cc = qt * 2; cc < qt * 2 + 2; cc++) {
    int c0 = cc * 64;
    for (int i = t; i < 4096; i += 256)
      sW[i] = Wo[(size_t)(c0 + (i >> 6)) * DIMC + h * DH + (i & 63)];
    __syncthreads();
    float a[4][4] = {};
    for (int egi = 0; egi < 16; egi++) {
      int eg = (egi + (t & 15)) & 15;
      float m4[4][4], wo4[4][4];
#pragma unroll
      for (int i = 0; i < 4; i++) *(float4*)m4[i] = *(const float4*)&sM[(dd0 + i) * 64 + eg * 4];
#pragma unroll
      for (int j = 0; j < 4; j++) *(float4*)wo4[j] = *(const float4*)&sW[(cl0 + j) * 64 + eg * 4];
#pragma unroll
      for (int i = 0; i < 4; i++)
#pragma unroll
        for (int j = 0; j < 4; j++)
#pragma unroll
          for (int ff = 0; ff < 4; ff++) a[i][j] = fmaf(m4[i][ff], wo4[j][ff], a[i][j]);
    }
#pragma unroll
    for (int j = 0; j < 4; j++) {
      uint2 pw = {pack_bf2(a[0][j], a[1][j]), pack_bf2(a[2][j], a[3][j])};
      *(uint2*)&WbigT[((size_t)b << 20) + (size_t)(c0 + cl0 + j) * DIMC + h * DH + dd0] = pw;
    }
    __syncthreads();
  }
}

// ---------------- Stage 3a: gemm, fp32-A fallback ---------------------------
__global__ __launch_bounds__(256, 3) void gemm_small(
    const float* __restrict__ x, const short* __restrict__ WbigT,
    const float* __restrict__ bo, float* __restrict__ out) {
  int bid = blockIdx.x;
  int xcd = bid & 7, r = bid >> 3;
  int g = r >> 5, q = r & 31;
  int m_blk = g * 32 + xcd * 4 + (q >> 3);
  int n_blk = q & 7;
  int b = m_blk >> 6;
  int row0 = m_blk * 128;
  int c0 = n_blk * 128;

  __shared__ __align__(16) short As[128 * 32];
  __shared__ __align__(16) short Bs[128 * 32];

  int t = threadIdx.x;
  int lane = t & 63, wave = t >> 6;
  int wm = wave >> 1, wn = wave & 1;
  int quad = lane >> 4, ln = lane & 15;

  f32x4 acc[4][4];
#pragma unroll
  for (int i = 0; i < 4; i++)
#pragma unroll
    for (int j = 0; j < 4; j++) acc[i][j] = (f32x4){0.f, 0.f, 0.f, 0.f};

  const short* Bbase = WbigT + ((size_t)b << 20);

  int e_base[2], crow_[2], lc_[2];
#pragma unroll
  for (int L = 0; L < 2; L++) {
    int e = (wave * 2 + L) * 512 + lane * 8;
    e_base[L] = e;
    int crow = e >> 5;
    crow_[L] = crow;
    lc_[L] = ((e >> 3) & 3) ^ ((crow >> 1) & 3);
  }

  for (int kt = 0; kt < 32; kt++) {
    int k0 = kt * 32;
    __syncthreads();
#pragma unroll
    for (int L = 0; L < 2; L++)
      gload_lds16(Bbase + (size_t)(c0 + crow_[L]) * DIMC + k0 + lc_[L] * 8, &Bs[e_base[L]]);
#pragma unroll
    for (int qq = 0; qq < 2; qq++) {
      int elem = qq * 2048 + wave * 512 + lane * 8;
      int m = elem >> 5, kk = elem & 31;
      const float* gp = x + (size_t)(row0 + m) * DIMC + k0 + kk;
      float4 v0 = *(const float4*)gp;
      float4 v1 = *(const float4*)(gp + 4);
      unsigned w0 = pack_bf2(v0.x, v0.y), w1 = pack_bf2(v0.z, v0.w);
      unsigned w2 = pack_bf2(v1.x, v1.y), w3 = pack_bf2(v1.z, v1.w);
      unsigned tmp[4] = {w0, w1, w2, w3};
      int pe = ((elem >> 3) & 3) ^ ((m >> 1) & 3);
      *(short8*)&As[m * 32 + pe * 8] = *(short8*)tmp;
    }
    __syncthreads();
    short8 afrag[4], bfrag[4];
#pragma unroll
    for (int i = 0; i < 4; i++) {
      int ar = wm * 64 + i * 16 + ln;
      afrag[i] = *(const short8*)&As[ar * 32 + (quad ^ ((ar >> 1) & 3)) * 8];
      int br = wn * 64 + i * 16 + ln;
      bfrag[i] = *(const short8*)&Bs[br * 32 + (quad ^ ((br >> 1) & 3)) * 8];
    }
#pragma unroll
    for (int i = 0; i < 4; i++)
#pragma unroll
      for (int j = 0; j < 4; j++)
        acc[i][j] = __builtin_amdgcn_mfma_f32_16x16x32_bf16(afrag[i], bfrag[j], acc[i][j], 0, 0, 0);
  }

  float bov[4];
#pragma unroll
  for (int j = 0; j < 4; j++) bov[j] = bo[c0 + wn * 64 + j * 16 + ln];
#pragma unroll
  for (int i = 0; i < 4; i++)
#pragma unroll
    for (int j = 0; j < 4; j++) {
      int col = c0 + wn * 64 + j * 16 + ln;
#pragma unroll
      for (int rr = 0; rr < 4; rr++) {
        int row = row0 + wm * 64 + i * 16 + quad * 4 + rr;
        out[(size_t)row * DIMC + col] = acc[i][j][rr] + bov[j];
      }
    }
}

// ---------------- Stage 3b: gemm, 128x128 tile, BK=64, m97 2-barrier loop ---
// Same proven structure as gemm_big (BK=32) but 64-wide K-step: identical
// total ds_read/MFMA/gload work, HALF the barrier count (16 vs 32) -> half
// the per-barrier vmcnt(0) drain stalls. Swizzle: 8 chunks/row, physical
// chunk cp holds logical cp^(row&7) (R1-R4-proven machinery, 0 conflicts).
__global__ __launch_bounds__(256, 3) void gemm_big64(
    const short* __restrict__ xbf, const short* __restrict__ WbigT,
    const float* __restrict__ bo, float* __restrict__ out) {
  int bid = blockIdx.x;
  int xcd = bid & 7, r = bid >> 3;
  int g = r >> 5, q = r & 31;
  int m_blk = g * 32 + xcd * 4 + (q >> 3);
  int n_blk = q & 7;
  int b = m_blk >> 6;
  int row0 = m_blk * 128;
  int c0 = n_blk * 128;

  __shared__ __align__(16) short As[128 * 64];
  __shared__ __align__(16) short Bs[128 * 64];

  int t = threadIdx.x;
  int lane = t & 63, wave = t >> 6;
  int wm = wave >> 1, wn = wave & 1;
  int quad = lane >> 4, ln = lane & 15;

  f32x4 acc[4][4];
#pragma unroll
  for (int i = 0; i < 4; i++)
#pragma unroll
    for (int j = 0; j < 4; j++) acc[i][j] = (f32x4){0.f, 0.f, 0.f, 0.f};

  const short* Bbase = WbigT + ((size_t)b << 20);

  // 1024 16B-chunks per tile per matrix; 4 issues/thread each.
  // physical slot p (row=p>>3, cp=p&7) holds logical chunk cp^(row&7).
  const short* Asrc[4];
  const short* Bsrc[4];
  int doff[4];
#pragma unroll
  for (int s = 0; s < 4; s++) {
    int p = s * 256 + t;
    int row = p >> 3;
    int cl = (p & 7) ^ (row & 7);
    doff[s] = p * 8;
    Asrc[s] = xbf + (size_t)(row0 + row) * DIMC + cl * 8;
    Bsrc[s] = Bbase + (size_t)(c0 + row) * DIMC + cl * 8;
  }

  for (int kt = 0; kt < 16; kt++) {
    int k0 = kt * 64;
    __syncthreads();
#pragma unroll
    for (int s = 0; s < 4; s++) gload_lds16(Asrc[s] + k0, &As[doff[s]]);
#pragma unroll
    for (int s = 0; s < 4; s++) gload_lds16(Bsrc[s] + k0, &Bs[doff[s]]);
    __syncthreads();
    short8 af[4][2], bf4[4][2];
#pragma unroll
    for (int i = 0; i < 4; i++) {
      int ar = wm * 64 + i * 16 + ln;
#pragma unroll
      for (int kk = 0; kk < 2; kk++)
        af[i][kk] = *(const short8*)&As[ar * 64 + (((kk * 4 + quad) ^ (ar & 7)) << 3)];
      int br = wn * 64 + i * 16 + ln;
#pragma unroll
      for (int kk = 0; kk < 2; kk++)
        bf4[i][kk] = *(const short8*)&Bs[br * 64 + (((kk * 4 + quad) ^ (br & 7)) << 3)];
    }
#pragma unroll
    for (int i = 0; i < 4; i++)
#pragma unroll
      for (int j = 0; j < 4; j++)
#pragma unroll
        for (int kk = 0; kk < 2; kk++)
          acc[i][j] = __builtin_amdgcn_mfma_f32_16x16x32_bf16(af[i][kk], bf4[j][kk], acc[i][j], 0, 0, 0);
  }

  float bov[4];
#pragma unroll
  for (int j = 0; j < 4; j++) bov[j] = bo[c0 + wn * 64 + j * 16 + ln];
#pragma unroll
  for (int i = 0; i < 4; i++)
#pragma unroll
    for (int j = 0; j < 4; j++) {
      int col = c0 + wn * 64 + j * 16 + ln;
#pragma unroll
      for (int rr = 0; rr < 4; rr++) {
        int row = row0 + wm * 64 + i * 16 + quad * 4 + rr;
        out[(size_t)row * DIMC + col] = acc[i][j][rr] + bov[j];
      }
    }
}

extern "C" void kernel_launch(void* const* d_in, const int* in_sizes, int n_in,
                              void* d_out, int out_size, void* d_ws, size_t ws_size,
                              hipStream_t stream) {
  const float* x  = (const float*)d_in[0];
  const float* Wq = (const float*)d_in[1];
  const float* Wk = (const float*)d_in[2];
  const float* Wv = (const float*)d_in[3];
  const float* Wo = (const float*)d_in[4];
  const float* bo = (const float*)d_in[5];
  float* out = (float*)d_out;
  (void)in_sizes; (void)n_in; (void)out_size;

  if (ws_size >= ((size_t)81 << 20)) {
    // big path: xbf 64 MiB | Gpart 8 MiB | G 1 MiB | WbigT 8 MiB (R6 structure)
    short* xbf   = (short*)d_ws;
    float* Gpart = (float*)((char*)d_ws + ((size_t)64 << 20));
    float* G     = (float*)((char*)d_ws + ((size_t)72 << 20));
    short* WbigT = (short*)((char*)d_ws + ((size_t)73 << 20));
    gram2_kernel<<<dim3(8, 64), 256, 0, stream>>>(x, Gpart, xbf);
    reduce_g<<<1024, 256, 0, stream>>>(Gpart, G, 8);
    combine_kernel<<<dim3(64, 8), 256, 0, stream>>>(G, Wq, Wk, Wv, Wo, WbigT);
    gemm_big64<<<2048, 256, 0, stream>>>(xbf, WbigT, bo, out);
  } else {
    // fallback: Gpart 32 MiB | G 1 MiB | WbigT 8 MiB (41 MiB, proven)
    float* Gpart = (float*)d_ws;
    float* G     = (float*)((char*)d_ws + ((size_t)32 << 20));
    short* WbigT = (short*)((char*)d_ws + ((size_t)33 << 20));
    gram_kernel<<<dim3(32, 64), 64, 0, stream>>>(x, Gpart, (short*)0);
    reduce_g<<<1024, 256, 0, stream>>>(Gpart, G, 32);
    combine_kernel<<<dim3(64, 8), 256, 0, stream>>>(G, Wq, Wk, Wv, Wo, WbigT);
    gemm_small<<<2048, 256, 0, stream>>>(x, WbigT, bo, out);
  }
}

// Round 10
// 354.069 us; speedup vs baseline: 1.0387x; 1.0089x over previous
//
#include <hip/hip_runtime.h>

#define DIMC 1024
#define NSEQ 8192
#define DH 64

typedef __attribute__((ext_vector_type(8))) short short8;
typedef __attribute__((ext_vector_type(4))) float f32x4;

__device__ __forceinline__ short f2bf(float f) {
  union { float f; unsigned u; } v; v.f = f;
  unsigned r = v.u + 0x7FFFu + ((v.u >> 16) & 1u);
  return (short)(r >> 16);
}

// pack two fp32 -> two bf16 (lo = a, hi = b); round-half-up, matches bfbits()
__device__ __forceinline__ unsigned pack_bf2(float a, float b) {
  union { float f; unsigned u; } va, vb;
  va.f = a; vb.f = b;
  unsigned ua = va.u + 0x8000u;
  unsigned ub = vb.u + 0x8000u;
  return (ua >> 16) | (ub & 0xFFFF0000u);
}

__device__ __forceinline__ unsigned bfbits(float f) {
  union { float f; unsigned u; } v; v.f = f;
  return (v.u + 0x8000u) >> 16;  // same rounding as pack_bf2
}
__device__ __forceinline__ float bf2f(unsigned hb) {
  union { unsigned u; float f; } v; v.u = hb << 16;
  return v.f;
}

__device__ __forceinline__ void gload_lds16(const void* g, void* l) {
  __builtin_amdgcn_global_load_lds(
      (const __attribute__((address_space(1))) void*)g,
      (__attribute__((address_space(3))) void*)l, 16, 0, 0);
}

// ---------------- Stage 1 (big path): MFMA Gram via hi/lo bf16 split -------
// G = X^T X per (b,h). x = x_hi + x_lo (bf16 each); G ~= H^T H + H^T L + L^T H
// (dropped L^T L ~ 2^-18 relative). Grid (8 chunks, 64 bh), 4 waves.
// In-block LDS reduction of the 4 wave-partials -> 8 global partials.
__global__ __launch_bounds__(256) void gram2_kernel(const float* __restrict__ x,
                                                    float* __restrict__ Gpart,
                                                    short* __restrict__ xbf) {
  int chunk = blockIdx.x, bh = blockIdx.y;
  int b = bh >> 4, h = bh & 15;
  int t = threadIdx.x;
  int w = t >> 6, l = t & 63;
  int quad = l >> 4, ln = l & 15;

  __shared__ __align__(16) short XT[4][2][64 * 32];  // [wave][hi/lo][d][k] 32 KiB
  __shared__ __align__(16) float Pred[3][4096];      // wave 1..3 partials, 48 KiB
  short* XH = &XT[w][0][0];
  short* XL = &XT[w][1][0];

  size_t rowbase = (size_t)b * NSEQ + (size_t)chunk * 1024 + w * 256;
  const float* xb = x + rowbase * DIMC + h * DH;
  short* xo = xbf + rowbase * DIMC + h * DH;

  f32x4 acc[4][4];
#pragma unroll
  for (int i = 0; i < 4; i++)
#pragma unroll
    for (int j = 0; j < 4; j++) acc[i][j] = (f32x4){0.f, 0.f, 0.f, 0.f};

  int woff[4][4];
#pragma unroll
  for (int q = 0; q < 4; q++) {
    int kk = 8 * q + 2 * quad;
    int kp = kk ^ ((ln & 3) << 3);
#pragma unroll
    for (int i = 0; i < 4; i++) {
      int d = ln * 4 + i;
      woff[q][i] = d * 32 + kp;
    }
  }
  int roff[4];
  {
    int k0 = (quad * 8) ^ ((ln >> 2) << 3);
#pragma unroll
    for (int i = 0; i < 4; i++) roff[i] = (i * 16 + ln) * 32 + k0;
  }

  float4 cur[4][2];
#pragma unroll
  for (int q = 0; q < 4; q++)
#pragma unroll
    for (int r = 0; r < 2; r++)
      cur[q][r] = *(const float4*)(xb + (size_t)(8 * q + 2 * quad + r) * DIMC + ln * 4);

  for (int ks = 0; ks < 8; ks++) {
    float4 nxt[4][2];
    if (ks < 7) {
      int nb = (ks + 1) * 32;
#pragma unroll
      for (int q = 0; q < 4; q++)
#pragma unroll
        for (int r = 0; r < 2; r++)
          nxt[q][r] = *(const float4*)(xb + (size_t)(nb + 8 * q + 2 * quad + r) * DIMC + ln * 4);
    }
#pragma unroll
    for (int q = 0; q < 4; q++) {
      unsigned h0[4], h1[4], l0[4], l1[4];
#pragma unroll
      for (int i = 0; i < 4; i++) {
        float a = cur[q][0][i], bb = cur[q][1][i];
        h0[i] = bfbits(a); l0[i] = bfbits(a - bf2f(h0[i]));
        h1[i] = bfbits(bb); l1[i] = bfbits(bb - bf2f(h1[i]));
      }
      int grow = ks * 32 + 8 * q + 2 * quad;
      uint2 p0 = {h0[0] | (h0[1] << 16), h0[2] | (h0[3] << 16)};
      uint2 p1 = {h1[0] | (h1[1] << 16), h1[2] | (h1[3] << 16)};
      *(uint2*)(xo + (size_t)grow * DIMC + ln * 4) = p0;
      *(uint2*)(xo + (size_t)(grow + 1) * DIMC + ln * 4) = p1;
#pragma unroll
      for (int i = 0; i < 4; i++) {
        *(unsigned*)&XH[woff[q][i]] = h0[i] | (h1[i] << 16);
        *(unsigned*)&XL[woff[q][i]] = l0[i] | (l1[i] << 16);
      }
    }
    short8 hf[4], lf[4];
#pragma unroll
    for (int i = 0; i < 4; i++) {
      hf[i] = *(const short8*)&XH[roff[i]];
      lf[i] = *(const short8*)&XL[roff[i]];
    }
#pragma unroll
    for (int i = 0; i < 4; i++)
#pragma unroll
      for (int j = 0; j < 4; j++) {
        acc[i][j] = __builtin_amdgcn_mfma_f32_16x16x32_bf16(hf[i], hf[j], acc[i][j], 0, 0, 0);
        acc[i][j] = __builtin_amdgcn_mfma_f32_16x16x32_bf16(hf[i], lf[j], acc[i][j], 0, 0, 0);
        acc[i][j] = __builtin_amdgcn_mfma_f32_16x16x32_bf16(lf[i], hf[j], acc[i][j], 0, 0, 0);
      }
#pragma unroll
    for (int q = 0; q < 4; q++)
#pragma unroll
      for (int r = 0; r < 2; r++) cur[q][r] = nxt[q][r];
  }

  // in-block reduction: waves 1-3 park partials in LDS, wave 0 merges + stores
  if (w > 0) {
    float* pd = &Pred[w - 1][0];
#pragma unroll
    for (int i = 0; i < 4; i++)
#pragma unroll
      for (int j = 0; j < 4; j++)
#pragma unroll
        for (int r = 0; r < 4; r++) {
          int d = i * 16 + quad * 4 + r, e = j * 16 + ln;
          pd[d * 64 + e] = acc[i][j][r];
        }
  }
  __syncthreads();
  if (w == 0) {
    float* gp = Gpart + (size_t)chunk * (64 * 4096) + (size_t)bh * 4096;
#pragma unroll
    for (int i = 0; i < 4; i++)
#pragma unroll
      for (int j = 0; j < 4; j++)
#pragma unroll
        for (int r = 0; r < 4; r++) {
          int d = i * 16 + quad * 4 + r, e = j * 16 + ln;
          int idx = d * 64 + e;
          gp[idx] = acc[i][j][r] + Pred[0][idx] + Pred[1][idx] + Pred[2][idx];
        }
  }
}

// ---------------- Stage 1 (fallback): fp32 Gram, no xbf ---------------------
__global__ __launch_bounds__(64) void gram_kernel(const float* __restrict__ x,
                                                  float* __restrict__ Gpart,
                                                  short* __restrict__ xbf) {
  int chunk = blockIdx.x, bh = blockIdx.y;
  int b = bh >> 4, h = bh & 15;
  int t = threadIdx.x;
  __shared__ __align__(16) float rows[16 * 64];
  const float* xb = x + ((size_t)b * NSEQ) * DIMC + h * DH;
  short* xo = xbf ? xbf + ((size_t)b * NSEQ) * DIMC + h * DH : (short*)0;
  int d0 = (t >> 3) * 8, e0 = (t & 7) * 8;
  float acc[8][8] = {};
  float4 v[4];
#pragma unroll
  for (int i = 0; i < 4; i++) {
    int f4 = i * 64 + t;
    v[i] = *(const float4*)(xb + (size_t)(chunk * 256 + (f4 >> 4)) * DIMC + (f4 & 15) * 4);
  }
  for (int it = 0; it < 16; it++) {
    __syncthreads();
#pragma unroll
    for (int i = 0; i < 4; i++) ((float4*)rows)[i * 64 + t] = v[i];
    __syncthreads();
    if (xo) {
#pragma unroll
      for (int i = 0; i < 4; i++) {
        int f4 = i * 64 + t;
        int row = chunk * 256 + it * 16 + (f4 >> 4), col = (f4 & 15) * 4;
        uint2 pw = {pack_bf2(v[i].x, v[i].y), pack_bf2(v[i].z, v[i].w)};
        *(uint2*)(xo + (size_t)row * DIMC + col) = pw;
      }
    }
    if (it < 15) {
      int nbase = chunk * 256 + (it + 1) * 16;
#pragma unroll
      for (int i = 0; i < 4; i++) {
        int f4 = i * 64 + t;
        v[i] = *(const float4*)(xb + (size_t)(nbase + (f4 >> 4)) * DIMC + (f4 & 15) * 4);
      }
    }
#pragma unroll
    for (int r = 0; r < 16; r++) {
      float xd[8], xe[8];
      *(float4*)&xd[0] = *(const float4*)&rows[r * 64 + d0];
      *(float4*)&xd[4] = *(const float4*)&rows[r * 64 + d0 + 4];
      *(float4*)&xe[0] = *(const float4*)&rows[r * 64 + e0];
      *(float4*)&xe[4] = *(const float4*)&rows[r * 64 + e0 + 4];
#pragma unroll
      for (int i = 0; i < 8; i++)
#pragma unroll
        for (int j = 0; j < 8; j++) acc[i][j] = fmaf(xd[i], xe[j], acc[i][j]);
    }
  }
  float* gp = Gpart + (size_t)chunk * (64 * 4096) + (size_t)bh * 4096;
#pragma unroll
  for (int i = 0; i < 8; i++)
#pragma unroll
    for (int j = 0; j < 8; j++) gp[(d0 + i) * 64 + e0 + j] = acc[i][j];
}

// ---------------- Stage 1b: reduce np partials -> G (fallback) --------------
__global__ void reduce_g(const float* __restrict__ Gpart, float* __restrict__ G,
                         int np) {
  int i = blockIdx.x * 256 + threadIdx.x;
  float s = 0.f;
  for (int p = 0; p < np; p++) s += Gpart[(size_t)p * (64 * 4096) + i];
  G[i] = s;
}

// ---------------- Stage 1b (big path): reduce + P = Wq^T*Wk (block 0) -------
// P is data-independent of G; block 0 computes it while 1023 siblings reduce.
__global__ __launch_bounds__(256) void reduce_gp(
    const float* __restrict__ Gpart, float* __restrict__ G, int np,
    const float* __restrict__ Wq, const float* __restrict__ Wk,
    float* __restrict__ P) {
  __shared__ __align__(16) float sq[4096];
  __shared__ __align__(16) float sk[4096];
  int i = blockIdx.x * 256 + threadIdx.x;
  float s = 0.f;
  for (int p = 0; p < np; p++) s += Gpart[(size_t)p * (64 * 4096) + i];
  G[i] = s;
  if (blockIdx.x == 0) {
    int t = threadIdx.x;
    for (int j = t; j < 4096; j += 256) { sq[j] = Wq[j]; sk[j] = Wk[j]; }
    __syncthreads();
    int d0 = (t >> 4) * 4, e0 = (t & 15) * 4;
    float a[4][4] = {};
    for (int f = 0; f < 64; f++) {
      float q4[4], k4[4];
      *(float4*)q4 = *(const float4*)&sq[f * 64 + d0];
      *(float4*)k4 = *(const float4*)&sk[f * 64 + e0];
#pragma unroll
      for (int ii = 0; ii < 4; ii++)
#pragma unroll
        for (int jj = 0; jj < 4; jj++) a[ii][jj] = fmaf(q4[ii], k4[jj], a[ii][jj]);
    }
#pragma unroll
    for (int ii = 0; ii < 4; ii++)
#pragma unroll
      for (int jj = 0; jj < 4; jj++) P[(d0 + ii) * 64 + e0 + jj] = a[ii][jj];
  }
}

// ---------------- Stage 2 (big path): combine using precomputed P ----------
// M = P*G*Wv^T/N (2 G-dependent matmuls instead of 3); all inputs loaded
// upfront (1 barrier), sP reused as the Wo staging buffer. 80 KiB LDS,
// 2 blocks/CU (same occupancy as before).
__global__ __launch_bounds__(256) void combine_p(
    const float* __restrict__ G, const float* __restrict__ P,
    const float* __restrict__ Wv, const float* __restrict__ Wo,
    short* __restrict__ WbigT) {
  int bh = blockIdx.x, qt = blockIdx.y;
  int b = bh >> 4, h = bh & 15;
  int t = threadIdx.x;
  __shared__ __align__(16) float sG[4096];
  __shared__ __align__(16) float sP[4096];  // P, later reused for Wo slices
  __shared__ __align__(16) float sV[4096];
  __shared__ __align__(16) float sT[4096];
  __shared__ __align__(16) float sM[4096];

  for (int i = t; i < 4096; i += 256) sG[i] = G[(size_t)bh * 4096 + i];
  for (int i = t; i < 4096; i += 256) sP[i] = P[i];
  for (int i = t; i < 4096; i += 256) sV[i] = Wv[i];
  __syncthreads();

  int d0 = (t >> 4) * 4, e0 = (t & 15) * 4;
  // T = P * G -> sT
  {
    float a[4][4] = {};
    for (int fg = 0; fg < 16; fg++) {
      float pk[4][4], g4[4][4];
#pragma unroll
      for (int i = 0; i < 4; i++) *(float4*)pk[i] = *(const float4*)&sP[(d0 + i) * 64 + fg * 4];
#pragma unroll
      for (int ff = 0; ff < 4; ff++) *(float4*)g4[ff] = *(const float4*)&sG[(fg * 4 + ff) * 64 + e0];
#pragma unroll
      for (int i = 0; i < 4; i++)
#pragma unroll
        for (int ff = 0; ff < 4; ff++)
#pragma unroll
          for (int j = 0; j < 4; j++) a[i][j] = fmaf(pk[i][ff], g4[ff][j], a[i][j]);
    }
#pragma unroll
    for (int i = 0; i < 4; i++)
#pragma unroll
      for (int j = 0; j < 4; j++) sT[(d0 + i) * 64 + e0 + j] = a[i][j];
  }
  __syncthreads();
  // M = T * Wv^T / N -> sM
  {
    float a[4][4] = {};
    for (int fgi = 0; fgi < 16; fgi++) {
      int fg = (fgi + (t & 15)) & 15;
      float t1[4][4], wv[4][4];
#pragma unroll
      for (int i = 0; i < 4; i++) *(float4*)t1[i] = *(const float4*)&sT[(d0 + i) * 64 + fg * 4];
#pragma unroll
      for (int j = 0; j < 4; j++) *(float4*)wv[j] = *(const float4*)&sV[(e0 + j) * 64 + fg * 4];
#pragma unroll
      for (int i = 0; i < 4; i++)
#pragma unroll
        for (int j = 0; j < 4; j++)
#pragma unroll
          for (int ff = 0; ff < 4; ff++) a[i][j] = fmaf(t1[i][ff], wv[j][ff], a[i][j]);
    }
#pragma unroll
    for (int i = 0; i < 4; i++)
#pragma unroll
      for (int j = 0; j < 4; j++) sM[(d0 + i) * 64 + e0 + j] = a[i][j] * (1.0f / 8192.0f);
  }
  __syncthreads();
  // Wo projection (identical loop; Wo slices staged into sP)
  int dd0 = (t & 15) * 4, cl0 = (t >> 4) * 4;
  for (int cc = qt * 2; cc < qt * 2 + 2; cc++) {
    int c0 = cc * 64;
    for (int i = t; i < 4096; i += 256)
      sP[i] = Wo[(size_t)(c0 + (i >> 6)) * DIMC + h * DH + (i & 63)];
    __syncthreads();
    float a[4][4] = {};
    for (int egi = 0; egi < 16; egi++) {
      int eg = (egi + (t & 15)) & 15;
      float m4[4][4], wo4[4][4];
#pragma unroll
      for (int i = 0; i < 4; i++) *(float4*)m4[i] = *(const float4*)&sM[(dd0 + i) * 64 + eg * 4];
#pragma unroll
      for (int j = 0; j < 4; j++) *(float4*)wo4[j] = *(const float4*)&sP[(cl0 + j) * 64 + eg * 4];
#pragma unroll
      for (int i = 0; i < 4; i++)
#pragma unroll
        for (int j = 0; j < 4; j++)
#pragma unroll
          for (int ff = 0; ff < 4; ff++) a[i][j] = fmaf(m4[i][ff], wo4[j][ff], a[i][j]);
    }
#pragma unroll
    for (int j = 0; j < 4; j++) {
      uint2 pw = {pack_bf2(a[0][j], a[1][j]), pack_bf2(a[2][j], a[3][j])};
      *(uint2*)&WbigT[((size_t)b << 20) + (size_t)(c0 + cl0 + j) * DIMC + h * DH + dd0] = pw;
    }
    __syncthreads();
  }
}

// ---------------- Stage 2 (fallback): original fused combine ----------------
__global__ __launch_bounds__(256) void combine_kernel(
    const float* __restrict__ G, const float* __restrict__ Wq,
    const float* __restrict__ Wk, const float* __restrict__ Wv,
    const float* __restrict__ Wo, short* __restrict__ WbigT) {
  int bh = blockIdx.x, qt = blockIdx.y;
  int b = bh >> 4, h = bh & 15;
  int t = threadIdx.x;
  __shared__ __align__(16) float sG[4096];
  __shared__ __align__(16) float sW[4096];
  __shared__ __align__(16) float sA[4096];
  __shared__ __align__(16) float sM[4096];

  for (int i = t; i < 4096; i += 256) sG[i] = G[(size_t)bh * 4096 + i];
  for (int i = t; i < 4096; i += 256) sW[i] = Wk[i];
  __syncthreads();

  int d0 = (t >> 4) * 4, e0 = (t & 15) * 4;
  {
    float a[4][4] = {};
    for (int fg = 0; fg < 16; fg++) {
      float wk[4][4], g4[4][4];
#pragma unroll
      for (int i = 0; i < 4; i++) *(float4*)wk[i] = *(const float4*)&sW[(d0 + i) * 64 + fg * 4];
#pragma unroll
      for (int ff = 0; ff < 4; ff++) *(float4*)g4[ff] = *(const float4*)&sG[(fg * 4 + ff) * 64 + e0];
#pragma unroll
      for (int i = 0; i < 4; i++)
#pragma unroll
        for (int ff = 0; ff < 4; ff++)
#pragma unroll
          for (int j = 0; j < 4; j++) a[i][j] = fmaf(wk[i][ff], g4[ff][j], a[i][j]);
    }
#pragma unroll
    for (int i = 0; i < 4; i++)
#pragma unroll
      for (int j = 0; j < 4; j++) sA[(d0 + i) * 64 + e0 + j] = a[i][j];
  }
  __syncthreads();
  for (int i = t; i < 4096; i += 256) sW[i] = Wv[i];
  __syncthreads();
  {
    float a[4][4] = {};
    for (int fgi = 0; fgi < 16; fgi++) {
      int fg = (fgi + (t & 15)) & 15;
      float t1[4][4], wv[4][4];
#pragma unroll
      for (int i = 0; i < 4; i++) *(float4*)t1[i] = *(const float4*)&sA[(d0 + i) * 64 + fg * 4];
#pragma unroll
      for (int j = 0; j < 4; j++) *(float4*)wv[j] = *(const float4*)&sW[(e0 + j) * 64 + fg * 4];
#pragma unroll
      for (int i = 0; i < 4; i++)
#pragma unroll
        for (int j = 0; j < 4; j++)
#pragma unroll
          for (int ff = 0; ff < 4; ff++) a[i][j] = fmaf(t1[i][ff], wv[j][ff], a[i][j]);
    }
    __syncthreads();
#pragma unroll
    for (int i = 0; i < 4; i++)
#pragma unroll
      for (int j = 0; j < 4; j++) sG[(d0 + i) * 64 + e0 + j] = a[i][j];
  }
  __syncthreads();
  for (int i = t; i < 4096; i += 256) sW[i] = Wq[i];
  __syncthreads();
  {
    float a[4][4] = {};
    for (int f = 0; f < 64; f++) {
      float wq[4], t2[4];
      *(float4*)wq = *(const float4*)&sW[f * 64 + d0];
      *(float4*)t2 = *(const float4*)&sG[f * 64 + e0];
#pragma unroll
      for (int i = 0; i < 4; i++)
#pragma unroll
        for (int j = 0; j < 4; j++) a[i][j] = fmaf(wq[i], t2[j], a[i][j]);
    }
#pragma unroll
    for (int i = 0; i < 4; i++)
#pragma unroll
      for (int j = 0; j < 4; j++) sM[(d0 + i) * 64 + e0 + j] = a[i][j] * (1.0f / 8192.0f);
  }
  __syncthreads();
  int dd0 = (t & 15) * 4, cl0 = (t >> 4) * 4;
  for (int cc = qt * 2; cc < qt * 2 + 2; cc++) {
    int c0 = cc * 64;
    for (int i = t; i < 4096; i += 256)
      sW[i] = Wo[(size_t)(c0 + (i >> 6)) * DIMC + h * DH + (i & 63)];
    __syncthreads();
    float a[4][4] = {};
    for (int egi = 0; egi < 16; egi++) {
      int eg = (egi + (t & 15)) & 15;
      float m4[4][4], wo4[4][4];
#pragma unroll
      for (int i = 0; i < 4; i++) *(float4*)m4[i] = *(const float4*)&sM[(dd0 + i) * 64 + eg * 4];
#pragma unroll
      for (int j = 0; j < 4; j++) *(float4*)wo4[j] = *(const float4*)&sW[(cl0 + j) * 64 + eg * 4];
#pragma unroll
      for (int i = 0; i < 4; i++)
#pragma unroll
        for (int j = 0; j < 4; j++)
#pragma unroll
          for (int ff = 0; ff < 4; ff++) a[i][j] = fmaf(m4[i][ff], wo4[j][ff], a[i][j]);
    }
#pragma unroll
    for (int j = 0; j < 4; j++) {
      uint2 pw = {pack_bf2(a[0][j], a[1][j]), pack_bf2(a[2][j], a[3][j])};
      *(uint2*)&WbigT[((size_t)b << 20) + (size_t)(c0 + cl0 + j) * DIMC + h * DH + dd0] = pw;
    }
    __syncthreads();
  }
}

// ---------------- Stage 3a: gemm, fp32-A fallback ---------------------------
__global__ __launch_bounds__(256, 3) void gemm_small(
    const float* __restrict__ x, const short* __restrict__ WbigT,
    const float* __restrict__ bo, float* __restrict__ out) {
  int bid = blockIdx.x;
  int xcd = bid & 7, r = bid >> 3;
  int g = r >> 5, q = r & 31;
  int m_blk = g * 32 + xcd * 4 + (q >> 3);
  int n_blk = q & 7;
  int b = m_blk >> 6;
  int row0 = m_blk * 128;
  int c0 = n_blk * 128;

  __shared__ __align__(16) short As[128 * 32];
  __shared__ __align__(16) short Bs[128 * 32];

  int t = threadIdx.x;
  int lane = t & 63, wave = t >> 6;
  int wm = wave >> 1, wn = wave & 1;
  int quad = lane >> 4, ln = lane & 15;

  f32x4 acc[4][4];
#pragma unroll
  for (int i = 0; i < 4; i++)
#pragma unroll
    for (int j = 0; j < 4; j++) acc[i][j] = (f32x4){0.f, 0.f, 0.f, 0.f};

  const short* Bbase = WbigT + ((size_t)b << 20);

  int e_base[2], crow_[2], lc_[2];
#pragma unroll
  for (int L = 0; L < 2; L++) {
    int e = (wave * 2 + L) * 512 + lane * 8;
    e_base[L] = e;
    int crow = e >> 5;
    crow_[L] = crow;
    lc_[L] = ((e >> 3) & 3) ^ ((crow >> 1) & 3);
  }

  for (int kt = 0; kt < 32; kt++) {
    int k0 = kt * 32;
    __syncthreads();
#pragma unroll
    for (int L = 0; L < 2; L++)
      gload_lds16(Bbase + (size_t)(c0 + crow_[L]) * DIMC + k0 + lc_[L] * 8, &Bs[e_base[L]]);
#pragma unroll
    for (int qq = 0; qq < 2; qq++) {
      int elem = qq * 2048 + wave * 512 + lane * 8;
      int m = elem >> 5, kk = elem & 31;
      const float* gp = x + (size_t)(row0 + m) * DIMC + k0 + kk;
      float4 v0 = *(const float4*)gp;
      float4 v1 = *(const float4*)(gp + 4);
      unsigned w0 = pack_bf2(v0.x, v0.y), w1 = pack_bf2(v0.z, v0.w);
      unsigned w2 = pack_bf2(v1.x, v1.y), w3 = pack_bf2(v1.z, v1.w);
      unsigned tmp[4] = {w0, w1, w2, w3};
      int pe = ((elem >> 3) & 3) ^ ((m >> 1) & 3);
      *(short8*)&As[m * 32 + pe * 8] = *(short8*)tmp;
    }
    __syncthreads();
    short8 afrag[4], bfrag[4];
#pragma unroll
    for (int i = 0; i < 4; i++) {
      int ar = wm * 64 + i * 16 + ln;
      afrag[i] = *(const short8*)&As[ar * 32 + (quad ^ ((ar >> 1) & 3)) * 8];
      int br = wn * 64 + i * 16 + ln;
      bfrag[i] = *(const short8*)&Bs[br * 32 + (quad ^ ((br >> 1) & 3)) * 8];
    }
#pragma unroll
    for (int i = 0; i < 4; i++)
#pragma unroll
      for (int j = 0; j < 4; j++)
        acc[i][j] = __builtin_amdgcn_mfma_f32_16x16x32_bf16(afrag[i], bfrag[j], acc[i][j], 0, 0, 0);
  }

  float bov[4];
#pragma unroll
  for (int j = 0; j < 4; j++) bov[j] = bo[c0 + wn * 64 + j * 16 + ln];
#pragma unroll
  for (int i = 0; i < 4; i++)
#pragma unroll
    for (int j = 0; j < 4; j++) {
      int col = c0 + wn * 64 + j * 16 + ln;
#pragma unroll
      for (int rr = 0; rr < 4; rr++) {
        int row = row0 + wm * 64 + i * 16 + quad * 4 + rr;
        out[(size_t)row * DIMC + col] = acc[i][j][rr] + bov[j];
      }
    }
}

// ---------------- Stage 3b: gemm, 128x128 tile, BK=64, m97 2-barrier loop ---
// (R9-proven: half the barrier count of BK=32 -> 85 us, MfmaUtil 35%, LOCKED)
__global__ __launch_bounds__(256, 3) void gemm_big64(
    const short* __restrict__ xbf, const short* __restrict__ WbigT,
    const float* __restrict__ bo, float* __restrict__ out) {
  int bid = blockIdx.x;
  int xcd = bid & 7, r = bid >> 3;
  int g = r >> 5, q = r & 31;
  int m_blk = g * 32 + xcd * 4 + (q >> 3);
  int n_blk = q & 7;
  int b = m_blk >> 6;
  int row0 = m_blk * 128;
  int c0 = n_blk * 128;

  __shared__ __align__(16) short As[128 * 64];
  __shared__ __align__(16) short Bs[128 * 64];

  int t = threadIdx.x;
  int lane = t & 63, wave = t >> 6;
  int wm = wave >> 1, wn = wave & 1;
  int quad = lane >> 4, ln = lane & 15;

  f32x4 acc[4][4];
#pragma unroll
  for (int i = 0; i < 4; i++)
#pragma unroll
    for (int j = 0; j < 4; j++) acc[i][j] = (f32x4){0.f, 0.f, 0.f, 0.f};

  const short* Bbase = WbigT + ((size_t)b << 20);

  const short* Asrc[4];
  const short* Bsrc[4];
  int doff[4];
#pragma unroll
  for (int s = 0; s < 4; s++) {
    int p = s * 256 + t;
    int row = p >> 3;
    int cl = (p & 7) ^ (row & 7);
    doff[s] = p * 8;
    Asrc[s] = xbf + (size_t)(row0 + row) * DIMC + cl * 8;
    Bsrc[s] = Bbase + (size_t)(c0 + row) * DIMC + cl * 8;
  }

  for (int kt = 0; kt < 16; kt++) {
    int k0 = kt * 64;
    __syncthreads();
#pragma unroll
    for (int s = 0; s < 4; s++) gload_lds16(Asrc[s] + k0, &As[doff[s]]);
#pragma unroll
    for (int s = 0; s < 4; s++) gload_lds16(Bsrc[s] + k0, &Bs[doff[s]]);
    __syncthreads();
    short8 af[4][2], bf4[4][2];
#pragma unroll
    for (int i = 0; i < 4; i++) {
      int ar = wm * 64 + i * 16 + ln;
#pragma unroll
      for (int kk = 0; kk < 2; kk++)
        af[i][kk] = *(const short8*)&As[ar * 64 + (((kk * 4 + quad) ^ (ar & 7)) << 3)];
      int br = wn * 64 + i * 16 + ln;
#pragma unroll
      for (int kk = 0; kk < 2; kk++)
        bf4[i][kk] = *(const short8*)&Bs[br * 64 + (((kk * 4 + quad) ^ (br & 7)) << 3)];
    }
#pragma unroll
    for (int i = 0; i < 4; i++)
#pragma unroll
      for (int j = 0; j < 4; j++)
#pragma unroll
        for (int kk = 0; kk < 2; kk++)
          acc[i][j] = __builtin_amdgcn_mfma_f32_16x16x32_bf16(af[i][kk], bf4[j][kk], acc[i][j], 0, 0, 0);
  }

  float bov[4];
#pragma unroll
  for (int j = 0; j < 4; j++) bov[j] = bo[c0 + wn * 64 + j * 16 + ln];
#pragma unroll
  for (int i = 0; i < 4; i++)
#pragma unroll
    for (int j = 0; j < 4; j++) {
      int col = c0 + wn * 64 + j * 16 + ln;
#pragma unroll
      for (int rr = 0; rr < 4; rr++) {
        int row = row0 + wm * 64 + i * 16 + quad * 4 + rr;
        out[(size_t)row * DIMC + col] = acc[i][j][rr] + bov[j];
      }
    }
}

extern "C" void kernel_launch(void* const* d_in, const int* in_sizes, int n_in,
                              void* d_out, int out_size, void* d_ws, size_t ws_size,
                              hipStream_t stream) {
  const float* x  = (const float*)d_in[0];
  const float* Wq = (const float*)d_in[1];
  const float* Wk = (const float*)d_in[2];
  const float* Wv = (const float*)d_in[3];
  const float* Wo = (const float*)d_in[4];
  const float* bo = (const float*)d_in[5];
  float* out = (float*)d_out;
  (void)in_sizes; (void)n_in; (void)out_size;

  if (ws_size >= ((size_t)83 << 20)) {
    // big path: xbf 64 | Gpart 8 (@64) | G 1 (@72) | P 1 (@73) | WbigT 8 (@74)
    short* xbf   = (short*)d_ws;
    float* Gpart = (float*)((char*)d_ws + ((size_t)64 << 20));
    float* G     = (float*)((char*)d_ws + ((size_t)72 << 20));
    float* P     = (float*)((char*)d_ws + ((size_t)73 << 20));
    short* WbigT = (short*)((char*)d_ws + ((size_t)74 << 20));
    gram2_kernel<<<dim3(8, 64), 256, 0, stream>>>(x, Gpart, xbf);
    reduce_gp<<<1024, 256, 0, stream>>>(Gpart, G, 8, Wq, Wk, P);
    combine_p<<<dim3(64, 8), 256, 0, stream>>>(G, P, Wv, Wo, WbigT);
    gemm_big64<<<2048, 256, 0, stream>>>(xbf, WbigT, bo, out);
  } else {
    // fallback: Gpart 32 MiB | G 1 MiB | WbigT 8 MiB (41 MiB, proven)
    float* Gpart = (float*)d_ws;
    float* G     = (float*)((char*)d_ws + ((size_t)32 << 20));
    short* WbigT = (short*)((char*)d_ws + ((size_t)33 << 20));
    gram_kernel<<<dim3(32, 64), 64, 0, stream>>>(x, Gpart, (short*)0);
    reduce_g<<<1024, 256, 0, stream>>>(Gpart, G, 32);
    combine_kernel<<<dim3(64, 8), 256, 0, stream>>>(G, Wq, Wk, Wv, Wo, WbigT);
    gemm_small<<<2048, 256, 0, stream>>>(x, WbigT, bo, out);
  }
}